// Round 6
// baseline (1685.792 us; speedup 1.0000x reference)
//
#include <hip/hip_runtime.h>
#include <hip/hip_bf16.h>

// PointConv SetAbstraction for MI355X. B=8,N=4096,S=1024,K=32,D=64.
#define BB 8
#define NN 4096
#define SS 1024
#define KK 32
#define PP (BB*SS*KK)   // 262144

typedef unsigned long long u64;
typedef unsigned int u32;
typedef unsigned short u16;
typedef float f32x2 __attribute__((ext_vector_type(2)));

// stats slots (each slot = 2 floats: sum, sumsq)
#define ST_Y0 0
#define ST_W0 64
#define ST_Y1 72
#define ST_W1 136
#define ST_Y2 144
#define ST_W2 272
#define ST_LIN 288
#define ST_TOTAL 416

static __device__ __forceinline__ float bf2f(u32 u){ return __uint_as_float(u<<16); }
static __device__ __forceinline__ u16 f2bf(float f){ u32 u=__float_as_uint(f); return (u16)((u + 0x7FFFu + ((u>>16)&1u))>>16); }

// packed fp32 math (bit-exact vs scalar: per-lane IEEE RN)
static __device__ __forceinline__ f32x2 pk_add(f32x2 a, f32x2 b){
  f32x2 d; asm("v_pk_add_f32 %0, %1, %2" : "=v"(d) : "v"(a), "v"(b)); return d;
}
static __device__ __forceinline__ f32x2 pk_mul(f32x2 a, f32x2 b){
  f32x2 d; asm("v_pk_mul_f32 %0, %1, %2" : "=v"(d) : "v"(a), "v"(b)); return d;
}

static __device__ __forceinline__ uint4 pack8(const float* v){
  uint4 r;
  r.x=(u32)f2bf(v[0])|((u32)f2bf(v[1])<<16);
  r.y=(u32)f2bf(v[2])|((u32)f2bf(v[3])<<16);
  r.z=(u32)f2bf(v[4])|((u32)f2bf(v[5])<<16);
  r.w=(u32)f2bf(v[6])|((u32)f2bf(v[7])<<16);
  return r;
}

// unpack 8 bf16 + affine + relu
static __device__ __forceinline__ void unp8_aff(uint4 r, const float* A, const float* C, int cb, float* o){
  o[0]=fmaxf(fmaf(bf2f(r.x&0xffffu),A[cb+0],C[cb+0]),0.f);
  o[1]=fmaxf(fmaf(bf2f(r.x>>16)    ,A[cb+1],C[cb+1]),0.f);
  o[2]=fmaxf(fmaf(bf2f(r.y&0xffffu),A[cb+2],C[cb+2]),0.f);
  o[3]=fmaxf(fmaf(bf2f(r.y>>16)    ,A[cb+3],C[cb+3]),0.f);
  o[4]=fmaxf(fmaf(bf2f(r.z&0xffffu),A[cb+4],C[cb+4]),0.f);
  o[5]=fmaxf(fmaf(bf2f(r.z>>16)    ,A[cb+5],C[cb+5]),0.f);
  o[6]=fmaxf(fmaf(bf2f(r.w&0xffffu),A[cb+6],C[cb+6]),0.f);
  o[7]=fmaxf(fmaf(bf2f(r.w>>16)    ,A[cb+7],C[cb+7]),0.f);
}

// ---------------- weight transpose prep (+ statsf zero-init) ----------------
__global__ void k_prep(const float* __restrict__ w0,const float* __restrict__ w1,const float* __restrict__ w2,
                       const float* __restrict__ ww0,const float* __restrict__ ww1,const float* __restrict__ ww2,
                       float* __restrict__ w0t,float* __restrict__ w1t,float* __restrict__ w2t,
                       float* __restrict__ wt0,float* __restrict__ wt1,float* __restrict__ wt2,
                       float* __restrict__ statsf){
  int t=threadIdx.x;
  for (int i=t;i<1024;i+=256) statsf[i]=0.f;
  for (int i=t;i<64*67;i+=256){ int o=i/67,k=i%67; w0t[k*64+o]=w0[i]; }
  for (int i=t;i<64*64;i+=256){ int o=i>>6,k=i&63; w1t[k*64+o]=w1[i]; }
  for (int i=t;i<128*64;i+=256){ int o=i>>6,k=i&63; w2t[k*128+o]=w2[i]; }
  for (int i=t;i<8*3;i+=256){ int o=i/3,k=i%3; wt0[k*8+o]=ww0[i]; }
  for (int i=t;i<8*8;i+=256){ int o=i>>3,k=i&7; wt1[k*8+o]=ww1[i]; }
  for (int i=t;i<16*8;i+=256){ int o=i>>3,k=i&7; wt2[k*16+o]=ww2[i]; }
}

// ---------------- FPS: registers-only points; coords travel through the LDS reduce ----------------
template<int CTRL, int RMASK>
static __device__ __forceinline__ u32 dppmax(u32 m){
  u32 t=(u32)__builtin_amdgcn_update_dpp(0, (int)m, CTRL, RMASK, 0xf, false);
  return t>m ? t : m;
}
static __device__ __forceinline__ void selkc(u64& k, float& x, float& y, float& z,
                                             u64 k2, float x2, float y2, float z2){
  bool g = k2>k;
  k = g?k2:k; x = g?x2:x; y = g?y2:y; z = g?z2:z;
}

__global__ __launch_bounds__(512) void k_fps(const float* __restrict__ xyz,
                                             float* __restrict__ fpsq, float* __restrict__ outx){
  __shared__ u64 redk[2][8];
  __shared__ float4 redc[2][8];
  int b=blockIdx.x, t=threadIdx.x;
  const float* xb=xyz+(size_t)b*3*NN;
  f32x2 px[4],py[4],pz[4],dd[4];
  {
    const float4* X4=(const float4*)xb;
    const float4* Y4=(const float4*)(xb+NN);
    const float4* Z4=(const float4*)(xb+2*NN);
    float4 a,c;
    a=X4[2*t]; c=X4[2*t+1];
    px[0].x=a.x;px[0].y=a.y; px[1].x=a.z;px[1].y=a.w;
    px[2].x=c.x;px[2].y=c.y; px[3].x=c.z;px[3].y=c.w;
    a=Y4[2*t]; c=Y4[2*t+1];
    py[0].x=a.x;py[0].y=a.y; py[1].x=a.z;py[1].y=a.w;
    py[2].x=c.x;py[2].y=c.y; py[3].x=c.z;py[3].y=c.w;
    a=Z4[2*t]; c=Z4[2*t+1];
    pz[0].x=a.x;pz[0].y=a.y; pz[1].x=a.z;pz[1].y=a.w;
    pz[2].x=c.x;pz[2].y=c.y; pz[3].x=c.z;pz[3].y=c.w;
  }
  #pragma unroll
  for (int k=0;k<4;k++){ dd[k].x=1e10f; dd[k].y=1e10f; }
  float fx=xb[0], fy=xb[NN], fz=xb[2*NN];
  int wv=t>>6, ln=t&63;
  for (int s=0;s<SS;s++){
    if (t==0){
      float* q=&fpsq[((size_t)b*SS+s)*3]; q[0]=fx;q[1]=fy;q[2]=fz;
      outx[b*3*SS+s]=fx; outx[b*3*SS+SS+s]=fy; outx[b*3*SS+2*SS+s]=fz;
    }
    f32x2 nfx,nfy,nfz;
    nfx.x=-fx;nfx.y=-fx; nfy.x=-fy;nfy.y=-fy; nfz.x=-fz;nfz.y=-fz;
    #pragma unroll
    for (int k=0;k<4;k++){
      f32x2 dx=pk_add(px[k],nfx);      // == px - fx (IEEE: a-b = a+(-b))
      f32x2 xx=pk_mul(dx,dx);
      f32x2 dy=pk_add(py[k],nfy);
      f32x2 yy=pk_mul(dy,dy);
      f32x2 dz=pk_add(pz[k],nfz);
      f32x2 zz=pk_mul(dz,dz);
      f32x2 s1=pk_add(xx,yy);
      f32x2 d2=pk_add(s1,zz);          // ((dx^2+dy^2)+dz^2), ref order
      dd[k].x=fminf(dd[k].x,d2.x);
      dd[k].y=fminf(dd[k].y,d2.y);
    }
    float m01=fmaxf(dd[0].x,dd[0].y), m23=fmaxf(dd[1].x,dd[1].y);
    float m45=fmaxf(dd[2].x,dd[2].y), m67=fmaxf(dd[3].x,dd[3].y);
    u32 m=__float_as_uint(fmaxf(fmaxf(m01,m23),fmaxf(m45,m67)));
    m=dppmax<0x111,0xf>(m);
    m=dppmax<0x112,0xf>(m);
    m=dppmax<0x114,0xf>(m);
    m=dppmax<0x118,0xf>(m);
    m=dppmax<0x142,0xa>(m);
    m=dppmax<0x143,0xc>(m);
    u32 wmax=(u32)__builtin_amdgcn_readlane((int)m,63);
    // lowest local j achieving wmax, with its coords (descending scan -> lowest wins)
    int gj=4096; float wx=0.f,wy=0.f,wz=0.f;
    bool e;
    e=(__float_as_uint(dd[3].y)==wmax); gj=e?(8*t+7):gj; wx=e?px[3].y:wx; wy=e?py[3].y:wy; wz=e?pz[3].y:wz;
    e=(__float_as_uint(dd[3].x)==wmax); gj=e?(8*t+6):gj; wx=e?px[3].x:wx; wy=e?py[3].x:wy; wz=e?pz[3].x:wz;
    e=(__float_as_uint(dd[2].y)==wmax); gj=e?(8*t+5):gj; wx=e?px[2].y:wx; wy=e?py[2].y:wy; wz=e?pz[2].y:wz;
    e=(__float_as_uint(dd[2].x)==wmax); gj=e?(8*t+4):gj; wx=e?px[2].x:wx; wy=e?py[2].x:wy; wz=e?pz[2].x:wz;
    e=(__float_as_uint(dd[1].y)==wmax); gj=e?(8*t+3):gj; wx=e?px[1].y:wx; wy=e?py[1].y:wy; wz=e?pz[1].y:wz;
    e=(__float_as_uint(dd[1].x)==wmax); gj=e?(8*t+2):gj; wx=e?px[1].x:wx; wy=e?py[1].x:wy; wz=e?pz[1].x:wz;
    e=(__float_as_uint(dd[0].y)==wmax); gj=e?(8*t+1):gj; wx=e?px[0].y:wx; wy=e?py[0].y:wy; wz=e?pz[0].y:wz;
    e=(__float_as_uint(dd[0].x)==wmax); gj=e?(8*t+0):gj; wx=e?px[0].x:wx; wy=e?py[0].x:wy; wz=e?pz[0].x:wz;
    u64 ball=__ballot(gj<4096);
    u32 wl=(u32)__builtin_ctzll(ball);            // lowest matching lane == lowest index
    u32 gi=(u32)__builtin_amdgcn_readlane(gj,(int)wl);
    float sx=__uint_as_float((u32)__builtin_amdgcn_readlane((int)__float_as_uint(wx),(int)wl));
    float sy=__uint_as_float((u32)__builtin_amdgcn_readlane((int)__float_as_uint(wy),(int)wl));
    float sz=__uint_as_float((u32)__builtin_amdgcn_readlane((int)__float_as_uint(wz),(int)wl));
    // key: dist desc, then lower idx wins; wave id in low bits keeps keys distinct
    u64 key=((u64)wmax<<32)|((u64)((4095u-gi)<<4))|(u64)wv;
    int pb=s&1;
    if (ln==0){ redk[pb][wv]=key; redc[pb][wv]=make_float4(sx,sy,sz,0.f); }
    __syncthreads();
    u64 k0=redk[pb][0],k1=redk[pb][1],k2=redk[pb][2],k3=redk[pb][3];
    u64 k4=redk[pb][4],k5=redk[pb][5],k6=redk[pb][6],k7=redk[pb][7];
    float4 c0=redc[pb][0],c1=redc[pb][1],c2=redc[pb][2],c3=redc[pb][3];
    float4 c4=redc[pb][4],c5=redc[pb][5],c6=redc[pb][6],c7=redc[pb][7];
    float x0=c0.x,y0_=c0.y,z0=c0.z;
    float x2=c2.x,y2_=c2.y,z2=c2.z;
    float x4=c4.x,y4_=c4.y,z4=c4.z;
    float x6=c6.x,y6_=c6.y,z6=c6.z;
    selkc(k0,x0,y0_,z0, k1,c1.x,c1.y,c1.z);
    selkc(k2,x2,y2_,z2, k3,c3.x,c3.y,c3.z);
    selkc(k4,x4,y4_,z4, k5,c5.x,c5.y,c5.z);
    selkc(k6,x6,y6_,z6, k7,c7.x,c7.y,c7.z);
    selkc(k0,x0,y0_,z0, k2,x2,y2_,z2);
    selkc(k4,x4,y4_,z4, k6,x6,y6_,z6);
    selkc(k0,x0,y0_,z0, k4,x4,y4_,z4);
    fx=x0; fy=y0_; fz=z0;
  }
}

// ---------------- feature transpose [B,64,N] -> [B,N,64] ----------------
__global__ __launch_bounds__(256) void k_featT(const float* __restrict__ f, float* __restrict__ ft){
  __shared__ float tile[64][65];
  int b=blockIdx.x>>6; int n0=(blockIdx.x&63)*64;
  const float* fb=f+(size_t)b*64*NN;
  int c0=threadIdx.x>>6, nn=threadIdx.x&63;
  #pragma unroll
  for (int it=0;it<16;it++){ int c=c0+it*4; tile[c][nn]=fb[(size_t)c*NN+n0+nn]; }
  __syncthreads();
  int cc=threadIdx.x&63, n1=threadIdx.x>>6;
  float* fo=ft+((size_t)b*NN+n0)*64;
  #pragma unroll
  for (int it=0;it<16;it++){ int n=n1+it*4; fo[(size_t)n*64+cc]=tile[cc][n]; }
}

// ---------------- KNN: top-32 of 4096 per query, one wave/query ----------------
#define KSTR 68
__global__ __launch_bounds__(256) void k_knn(const float* __restrict__ xyz, const float* __restrict__ fpsq,
                                             int* __restrict__ kidx){
  extern __shared__ char smem[];
  float* xs=(float*)smem;
  float* ys=xs+64*KSTR;
  float* zs=ys+64*KSTR;
  float* pn=zs+64*KSTR;
  int blk=blockIdx.x; int b=blk>>8; int s0=(blk&255)*4;
  const float* xb=xyz+(size_t)b*3*NN;
  for (int i=threadIdx.x;i<NN;i+=256){
    float x=xb[i],y=xb[NN+i],z=xb[2*NN+i];
    int slot=(i>>6)*KSTR+(i&63);
    xs[slot]=x; ys[slot]=y; zs[slot]=z;
    pn[slot]=__fadd_rn(__fadd_rn(__fmul_rn(x,x),__fmul_rn(y,y)),__fmul_rn(z,z));
  }
  __syncthreads();
  int wv=threadIdx.x>>6, ln=threadIdx.x&63;
  int s=s0+wv;
  const float* q=&fpsq[((size_t)b*SS+s)*3];
  float qx=q[0],qy=q[1],qz=q[2];
  float qn=__fadd_rn(__fadd_rn(__fmul_rn(qx,qx),__fmul_rn(qy,qy)),__fmul_rn(qz,qz));
  f32x2 qxx,qyy,qzz,qnn,mtwo;
  qxx.x=qx;qxx.y=qx; qyy.x=qy;qyy.y=qy; qzz.x=qz;qzz.y=qz; qnn.x=qn;qnn.y=qn;
  mtwo.x=-2.f; mtwo.y=-2.f;
  const float4* Xp=(const float4*)(xs+ln*KSTR);
  const float4* Yp=(const float4*)(ys+ln*KSTR);
  const float4* Zp=(const float4*)(zs+ln*KSTR);
  const float4* Pp=(const float4*)(pn+ln*KSTR);
  int base=ln*64;
  u64 v[64];
  #pragma unroll
  for (int g=0;g<16;g++){
    float4 x4=Xp[g], y4=Yp[g], z4=Zp[g], p4=Pp[g];
    #pragma unroll
    for (int h=0;h<2;h++){
      f32x2 px2,py2,pz2,pn2;
      if (h==0){ px2.x=x4.x;px2.y=x4.y; py2.x=y4.x;py2.y=y4.y; pz2.x=z4.x;pz2.y=z4.y; pn2.x=p4.x;pn2.y=p4.y; }
      else     { px2.x=x4.z;px2.y=x4.w; py2.x=y4.z;py2.y=y4.w; pz2.x=z4.z;pz2.y=z4.w; pn2.x=p4.z;pn2.y=p4.w; }
      f32x2 m1=pk_mul(qxx,px2);
      f32x2 mm=pk_mul(qyy,py2);
      f32x2 a1=pk_add(m1,mm);
      f32x2 m3=pk_mul(qzz,pz2);
      f32x2 dt=pk_add(a1,m3);           // (qx*px+qy*py)+qz*pz, ref order
      f32x2 qp=pk_add(qnn,pn2);         // qn+pn
      f32x2 nd=pk_mul(dt,mtwo);         // -(2*dt) bit-exact
      f32x2 d2=pk_add(qp,nd);           // (qn+pn)-2*dt
      #pragma unroll
      for (int e=0;e<2;e++){
        u32 bu=__float_as_uint(e?d2.y:d2.x);
        bu = ((int)bu<0)? ~bu : (bu|0x80000000u);
        v[g*4+h*2+e]=((u64)bu<<32)|(u32)(base+g*4+h*2+e);
      }
    }
  }
  u64 cand[8];
  #pragma unroll
  for (int gg=0;gg<8;gg++){
    u64 c=v[gg*8];
    #pragma unroll
    for (int j=1;j<8;j++){ u64 x=v[gg*8+j]; c = x<c?x:c; }
    cand[gg]=c;
  }
  u64 best=cand[0];
  #pragma unroll
  for (int gg=1;gg<8;gg++){ u64 x=cand[gg]; best = x<best?x:best; }
  int my=0;
  #pragma unroll 1
  for (int r=0;r<KK;r++){
    u64 w=best;
    #pragma unroll
    for (int m=1;m<64;m<<=1){ u64 o=__shfl_xor(w,m,64); w = o<w?o:w; }
    if (ln==r) my=(int)(w&0xFFFull);
    if (best==w){
      #pragma unroll
      for (int gg=0;gg<8;gg++){
        if (cand[gg]==w){
          u64 c=~0ull;
          #pragma unroll
          for (int j=0;j<8;j++){ u64 x=v[gg*8+j]; x = x>w ? x : ~0ull; c = x<c?x:c; }
          cand[gg]=c;
        }
      }
      u64 nb=cand[0];
      #pragma unroll
      for (int gg=1;gg<8;gg++){ u64 x=cand[gg]; nb = x<nb?x:nb; }
      best=nb;
    }
  }
  if (ln<KK) kidx[(((size_t)b*SS+s)<<5)+ln]=my;
}

// ---------------- layer 0: gather + 67->64 + wnet 3->8 ----------------
__global__ __launch_bounds__(256) void k_l0(const float* __restrict__ xyz, const float* __restrict__ ft,
    const float* __restrict__ fpsq, const int* __restrict__ kidx,
    const float* __restrict__ w0t, const float* __restrict__ wt0,
    u16* __restrict__ y0, float* __restrict__ wl0){
  int p=blockIdx.x*256+threadIdx.x;
  int b=p>>15;
  int site=p>>5;
  int j=kidx[p];
  const float* xb=xyz+(size_t)b*3*NN;
  const float* q=fpsq+(size_t)site*3;
  float gx=xb[j]-q[0], gy=xb[NN+j]-q[1], gz=xb[2*NN+j]-q[2];
  float acc[64];
  #pragma unroll
  for (int c=0;c<64;c++) acc[c]=fmaf(gx,w0t[c],fmaf(gy,w0t[64+c],gz*w0t[128+c]));
  const float4* fr=(const float4*)(ft+((size_t)b*NN+j)*64);
  #pragma unroll 1
  for (int kb=0;kb<4;kb++){
    float4 r0=fr[kb*4+0], r1=fr[kb*4+1], r2=fr[kb*4+2], r3=fr[kb*4+3];
    float ch[16]={r0.x,r0.y,r0.z,r0.w,r1.x,r1.y,r1.z,r1.w,r2.x,r2.y,r2.z,r2.w,r3.x,r3.y,r3.z,r3.w};
    const float* wb=w0t+(3+kb*16)*64;
    #pragma unroll
    for (int kk=0;kk<16;kk++){
      #pragma unroll
      for (int c=0;c<64;c++) acc[c]=fmaf(ch[kk],wb[kk*64+c],acc[c]);
    }
  }
  u16* yr=y0+(size_t)p*64;
  #pragma unroll
  for (int c8=0;c8<8;c8++) ((uint4*)yr)[c8]=pack8(&acc[c8*8]);
  float wa[8];
  #pragma unroll
  for (int o=0;o<8;o++) wa[o]=fmaf(gx,wt0[o],fmaf(gy,wt0[8+o],gz*wt0[16+o]));
  float4* wr=(float4*)(wl0+(size_t)p*8);
  wr[0]=make_float4(wa[0],wa[1],wa[2],wa[3]);
  wr[1]=make_float4(wa[4],wa[5],wa[6],wa[7]);
}

// ---------------- paired column stats: y (bf16) + w (f32) in one dispatch ----------------
#define STATS_YB 896
__global__ __launch_bounds__(256) void k_stats2(const u16* __restrict__ yb, int nchy,
                                                const float* __restrict__ wb, int nchw,
                                                float* __restrict__ outy, float* __restrict__ outw){
  __shared__ float lds[4][256];   // [wave][0..127]=sum, [128..255]=sumsq
  int t=threadIdx.x; int wv=t>>6, ln=t&63;
  float s[8]={0,0,0,0,0,0,0,0}, q[8]={0,0,0,0,0,0,0,0};
  int isbf = blockIdx.x < STATS_YB;
  int bid  = isbf ? blockIdx.x : (blockIdx.x - STATS_YB);
  int nb   = isbf ? STATS_YB : (gridDim.x - STATS_YB);
  int nch  = isbf ? nchy : nchw;
  float* out = isbf ? outy : outw;
  int E = isbf ? 8 : 4;
  int L = nch / E;
  int lir=t&(L-1);
  int rib=t/L;
  int rpb=256/L;
  int r=bid*rpb+rib;
  int rstride=nb*rpb;
  if (isbf){
    const u16* u=yb;
    for (; r<PP; r+=rstride){
      uint4 raw=*(const uint4*)(u+(size_t)r*nch+lir*8);
      float v0=bf2f(raw.x&0xffffu), v1=bf2f(raw.x>>16);
      float v2=bf2f(raw.y&0xffffu), v3=bf2f(raw.y>>16);
      float v4=bf2f(raw.z&0xffffu), v5=bf2f(raw.z>>16);
      float v6=bf2f(raw.w&0xffffu), v7=bf2f(raw.w>>16);
      s[0]+=v0; q[0]=fmaf(v0,v0,q[0]);
      s[1]+=v1; q[1]=fmaf(v1,v1,q[1]);
      s[2]+=v2; q[2]=fmaf(v2,v2,q[2]);
      s[3]+=v3; q[3]=fmaf(v3,v3,q[3]);
      s[4]+=v4; q[4]=fmaf(v4,v4,q[4]);
      s[5]+=v5; q[5]=fmaf(v5,v5,q[5]);
      s[6]+=v6; q[6]=fmaf(v6,v6,q[6]);
      s[7]+=v7; q[7]=fmaf(v7,v7,q[7]);
    }
  } else {
    const float* f=wb;
    for (; r<PP; r+=rstride){
      float4 v=*(const float4*)(f+(size_t)r*nch+lir*4);
      s[0]+=v.x; q[0]=fmaf(v.x,v.x,q[0]);
      s[1]+=v.y; q[1]=fmaf(v.y,v.y,q[1]);
      s[2]+=v.z; q[2]=fmaf(v.z,v.z,q[2]);
      s[3]+=v.w; q[3]=fmaf(v.w,v.w,q[3]);
    }
  }
  for (int m=L; m<64; m<<=1){
    #pragma unroll
    for (int e=0;e<8;e++){
      s[e]+=__shfl_xor(s[e],m,64);
      q[e]+=__shfl_xor(q[e],m,64);
    }
  }
  if (ln<L){
    int cb=ln*E;
    #pragma unroll
    for (int e=0;e<8;e++){
      if (e<E){ lds[wv][cb+e]=s[e]; lds[wv][128+cb+e]=q[e]; }
    }
  }
  __syncthreads();
  if (t<nch){
    float S=lds[0][t]+lds[1][t]+lds[2][t]+lds[3][t];
    float Q=lds[0][128+t]+lds[1][128+t]+lds[2][128+t]+lds[3][128+t];
    atomicAdd(&out[2*t],S); atomicAdd(&out[2*t+1],Q);
  }
}

// ---------------- layer 1: BN0+relu -> 64->64 ; wnet BN+relu 8->8 ----------------
__global__ __launch_bounds__(256) void k_l1(const u16* __restrict__ y0, const float* __restrict__ wl0,
    const float* __restrict__ w1t, const float* __restrict__ wt1,
    const float* __restrict__ statsf,
    const float* __restrict__ g0v, const float* __restrict__ be0v,
    const float* __restrict__ wg0v, const float* __restrict__ wbe0v,
    u16* __restrict__ y1, float* __restrict__ wl1){
  __shared__ float A0[64],C0[64],AW[8],CW[8];
  int t=threadIdx.x;
  if (t<64){
    float sm=statsf[(ST_Y0+t)*2], sq=statsf[(ST_Y0+t)*2+1];
    float mean=sm*(1.f/PP), var=fmaxf(sq*(1.f/PP)-mean*mean,0.f);
    float a=g0v[t]*rsqrtf(var+1e-5f); A0[t]=a; C0[t]=be0v[t]-mean*a;
  } else if (t<72){
    int c=t-64;
    float sm=statsf[(ST_W0+c)*2], sq=statsf[(ST_W0+c)*2+1];
    float mean=sm*(1.f/PP), var=fmaxf(sq*(1.f/PP)-mean*mean,0.f);
    float a=wg0v[c]*rsqrtf(var+1e-5f); AW[c]=a; CW[c]=wbe0v[c]-mean*a;
  }
  __syncthreads();
  int p=blockIdx.x*256+t;
  const uint4* yr=(const uint4*)(y0+(size_t)p*64);
  float acc[64];
  #pragma unroll
  for (int c=0;c<64;c++) acc[c]=0.f;
  #pragma unroll 1
  for (int kb=0;kb<4;kb++){
    uint4 r0=yr[kb*2], r1=yr[kb*2+1];
    float ch[16];
    unp8_aff(r0,A0,C0,kb*16,ch);
    unp8_aff(r1,A0,C0,kb*16+8,ch+8);
    const float* wb=w1t+kb*16*64;
    #pragma unroll
    for (int kk=0;kk<16;kk++){
      #pragma unroll
      for (int c=0;c<64;c++) acc[c]=fmaf(ch[kk],wb[kk*64+c],acc[c]);
    }
  }
  u16* yo=y1+(size_t)p*64;
  #pragma unroll
  for (int c8=0;c8<8;c8++) ((uint4*)yo)[c8]=pack8(&acc[c8*8]);
  const float4* wvp=(const float4*)(wl0+(size_t)p*8);
  float4 v0=wvp[0], v1=wvp[1];
  float wi[8]={v0.x,v0.y,v0.z,v0.w,v1.x,v1.y,v1.z,v1.w};
  float wo[8];
  #pragma unroll
  for (int o=0;o<8;o++) wo[o]=0.f;
  #pragma unroll
  for (int k=0;k<8;k++){
    float xr=fmaxf(fmaf(wi[k],AW[k],CW[k]),0.f);
    #pragma unroll
    for (int o=0;o<8;o++) wo[o]=fmaf(xr,wt1[k*8+o],wo[o]);
  }
  float4* wr=(float4*)(wl1+(size_t)p*8);
  wr[0]=make_float4(wo[0],wo[1],wo[2],wo[3]);
  wr[1]=make_float4(wo[4],wo[5],wo[6],wo[7]);
}

// ---------------- layer 2: BN1+relu -> 64->128 ; wnet BN+relu 8->16 ----------------
__global__ __launch_bounds__(256) void k_l2(const u16* __restrict__ y1, const float* __restrict__ wl1,
    const float* __restrict__ w2t, const float* __restrict__ wt2,
    const float* __restrict__ statsf,
    const float* __restrict__ g1v, const float* __restrict__ be1v,
    const float* __restrict__ wg1v, const float* __restrict__ wbe1v,
    u16* __restrict__ y2, float* __restrict__ wl2){
  __shared__ float A1[64],C1[64],AW[8],CW[8];
  int t=threadIdx.x;
  if (t<64){
    float sm=statsf[(ST_Y1+t)*2], sq=statsf[(ST_Y1+t)*2+1];
    float mean=sm*(1.f/PP), var=fmaxf(sq*(1.f/PP)-mean*mean,0.f);
    float a=g1v[t]*rsqrtf(var+1e-5f); A1[t]=a; C1[t]=be1v[t]-mean*a;
  } else if (t<72){
    int c=t-64;
    float sm=statsf[(ST_W1+c)*2], sq=statsf[(ST_W1+c)*2+1];
    float mean=sm*(1.f/PP), var=fmaxf(sq*(1.f/PP)-mean*mean,0.f);
    float a=wg1v[c]*rsqrtf(var+1e-5f); AW[c]=a; CW[c]=wbe1v[c]-mean*a;
  }
  __syncthreads();
  int p=blockIdx.x*256+t;
  const uint4* yr=(const uint4*)(y1+(size_t)p*64);
  #pragma unroll 1
  for (int h=0;h<2;h++){
    float acc[64];
    #pragma unroll
    for (int c=0;c<64;c++) acc[c]=0.f;
    #pragma unroll 1
    for (int kb=0;kb<4;kb++){
      uint4 r0=yr[kb*2], r1=yr[kb*2+1];
      float ch[16];
      unp8_aff(r0,A1,C1,kb*16,ch);
      unp8_aff(r1,A1,C1,kb*16+8,ch+8);
      const float* wb=w2t+(size_t)kb*16*128+h*64;
      #pragma unroll
      for (int kk=0;kk<16;kk++){
        #pragma unroll
        for (int c=0;c<64;c++) acc[c]=fmaf(ch[kk],wb[kk*128+c],acc[c]);
      }
    }
    u16* yo=y2+(size_t)p*128+h*64;
    #pragma unroll
    for (int c8=0;c8<8;c8++) ((uint4*)yo)[c8]=pack8(&acc[c8*8]);
  }
  const float4* wvp=(const float4*)(wl1+(size_t)p*8);
  float4 v0=wvp[0], v1=wvp[1];
  float wi[8]={v0.x,v0.y,v0.z,v0.w,v1.x,v1.y,v1.z,v1.w};
  float wo[16];
  #pragma unroll
  for (int o=0;o<16;o++) wo[o]=0.f;
  #pragma unroll
  for (int k=0;k<8;k++){
    float xr=fmaxf(fmaf(wi[k],AW[k],CW[k]),0.f);
    #pragma unroll
    for (int o=0;o<16;o++) wo[o]=fmaf(xr,wt2[k*16+o],wo[o]);
  }
  float4* wr=(float4*)(wl2+(size_t)p*16);
  wr[0]=make_float4(wo[0],wo[1],wo[2],wo[3]);
  wr[1]=make_float4(wo[4],wo[5],wo[6],wo[7]);
  wr[2]=make_float4(wo[8],wo[9],wo[10],wo[11]);
  wr[3]=make_float4(wo[12],wo[13],wo[14],wo[15]);
}

// ---------------- agg: per site, BN2+relu both, outer-product pooled over k ----------------
__global__ __launch_bounds__(256) void k_agg(const u16* __restrict__ y2, const float* __restrict__ wl2,
    const float* __restrict__ statsf,
    const float* __restrict__ g2v, const float* __restrict__ be2v,
    const float* __restrict__ wg2v, const float* __restrict__ wbe2v,
    u16* __restrict__ agg){
  __shared__ float A2[128],C2[128],AW[16],CW[16];
  __shared__ float nf[32*128];
  __shared__ float wt[32*16];
  int site=blockIdx.x; int t=threadIdx.x;
  if (t<128){
    float sm=statsf[(ST_Y2+t)*2], sq=statsf[(ST_Y2+t)*2+1];
    float mean=sm*(1.f/PP), var=fmaxf(sq*(1.f/PP)-mean*mean,0.f);
    float a=g2v[t]*rsqrtf(var+1e-5f); A2[t]=a; C2[t]=be2v[t]-mean*a;
  } else if (t<144){
    int c=t-128;
    float sm=statsf[(ST_W2+c)*2], sq=statsf[(ST_W2+c)*2+1];
    float mean=sm*(1.f/PP), var=fmaxf(sq*(1.f/PP)-mean*mean,0.f);
    float a=wg2v[c]*rsqrtf(var+1e-5f); AW[c]=a; CW[c]=wbe2v[c]-mean*a;
  }
  __syncthreads();
  const uint4* src=(const uint4*)(y2+(size_t)site*32*128);
  #pragma unroll
  for (int it=0;it<2;it++){
    int idx=t+it*256;
    uint4 r=src[idx];
    int base=(idx*8)&127; int kq=(idx*8)>>7;
    unp8_aff(r,A2,C2,base,&nf[kq*128+base]);
  }
  #pragma unroll
  for (int it=0;it<2;it++){
    int i=t+it*256;
    float x=wl2[(size_t)site*512+i]; int c=i&15;
    wt[i]=fmaxf(fmaf(x,AW[c],CW[c]),0.f);
  }
  __syncthreads();
  int d=t>>1, cb=(t&1)*8;
  float acc[8];
  #pragma unroll
  for (int e=0;e<8;e++) acc[e]=0.f;
  #pragma unroll 4
  for (int kq=0;kq<32;kq++){
    float nv=nf[kq*128+d];
    #pragma unroll
    for (int e=0;e<8;e++) acc[e]=fmaf(nv,wt[kq*16+cb+e],acc[e]);
  }
  ((uint4*)(agg+(size_t)site*2048))[t]=pack8(acc);
}

// ---------------- linear: [8192 x 2048] @ lw^T -> [8192 x 128], fused lin-stats ----------------
__global__ __launch_bounds__(256) void k_lin(const u16* __restrict__ agg, const float* __restrict__ lw,
                                             float* __restrict__ lin, float* __restrict__ outst){
  __shared__ float As[32][33];
  __shared__ float Bs[32][128];
  __shared__ float stS[8][132], stQ[8][132];
  int s0=blockIdx.x*32; int t=threadIdx.x;
  int tx=t&31, ty=t>>5;
  float acc[4][4];
  #pragma unroll
  for (int i=0;i<4;i++){
    #pragma unroll
    for (int jj=0;jj<4;jj++) acc[i][jj]=0.f;
  }
  for (int kb=0;kb<2048;kb+=32){
    {
      int row=t>>3, kc=(t&7)*4;
      uint2 raw=*(const uint2*)(agg+((size_t)(s0+row))*2048+kb+kc);
      As[row][kc  ]=bf2f(raw.x&0xffffu); As[row][kc+1]=bf2f(raw.x>>16);
      As[row][kc+2]=bf2f(raw.y&0xffffu); As[row][kc+3]=bf2f(raw.y>>16);
    }
    {
      int o=t>>1, ks=(t&1)*16;
      const float* lr=lw+(size_t)o*2048+kb+ks;
      #pragma unroll
      for (int i=0;i<16;i+=4){
        float4 r=*(const float4*)(lr+i);
        Bs[ks+i][o]=r.x; Bs[ks+i+1][o]=r.y; Bs[ks+i+2][o]=r.z; Bs[ks+i+3][o]=r.w;
      }
    }
    __syncthreads();
    #pragma unroll 8
    for (int kk=0;kk<32;kk++){
      float av[4];
      #pragma unroll
      for (int i=0;i<4;i++) av[i]=As[ty*4+i][kk];
      float4 bv=*(const float4*)(&Bs[kk][tx*4]);
      #pragma unroll
      for (int i=0;i<4;i++){
        acc[i][0]=fmaf(av[i],bv.x,acc[i][0]);
        acc[i][1]=fmaf(av[i],bv.y,acc[i][1]);
        acc[i][2]=fmaf(av[i],bv.z,acc[i][2]);
        acc[i][3]=fmaf(av[i],bv.w,acc[i][3]);
      }
    }
    __syncthreads();
  }
  #pragma unroll
  for (int i=0;i<4;i++){
    float4 o4=make_float4(acc[i][0],acc[i][1],acc[i][2],acc[i][3]);
    *(float4*)(lin+((size_t)(s0+ty*4+i))*128+tx*4)=o4;
  }
  // fused per-block column stats over the 32 rows this block produced
  #pragma unroll
  for (int jj=0;jj<4;jj++){
    float a0=acc[0][jj],a1=acc[1][jj],a2=acc[2][jj],a3=acc[3][jj];
    stS[ty][tx*4+jj]=(a0+a1)+(a2+a3);
    stQ[ty][tx*4+jj]=fmaf(a3,a3,fmaf(a2,a2,fmaf(a1,a1,a0*a0)));
  }
  __syncthreads();
  if (t<128){
    float S=0.f,Q=0.f;
    #pragma unroll
    for (int k=0;k<8;k++){ S+=stS[k][t]; Q+=stQ[k][t]; }
    atomicAdd(&outst[2*t],S); atomicAdd(&outst[2*t+1],Q);
  }
}

// ---------------- final BN + relu + transpose -> out [B,128,S] ----------------
__global__ __launch_bounds__(256) void k_out(const float* __restrict__ lin, const float* __restrict__ statsf,
    const float* __restrict__ lg, const float* __restrict__ lbe, float* __restrict__ outf){
  int t=blockIdx.x*256+threadIdx.x;  // 262144 = 8*128*256
  int s4=(t&255)*4; int o=(t>>8)&127; int b=t>>15;
  float sm=statsf[(ST_LIN+o)*2], sq=statsf[(ST_LIN+o)*2+1];
  float mean=sm*(1.f/8192.f), var=fmaxf(sq*(1.f/8192.f)-mean*mean,0.f);
  float a=lg[o]*rsqrtf(var+1e-5f), cc=lbe[o]-mean*a;
  float v0=lin[((size_t)b*SS+s4+0)*128+o];
  float v1=lin[((size_t)b*SS+s4+1)*128+o];
  float v2=lin[((size_t)b*SS+s4+2)*128+o];
  float v3=lin[((size_t)b*SS+s4+3)*128+o];
  float4 r=make_float4(fmaxf(fmaf(v0,a,cc),0.f),fmaxf(fmaf(v1,a,cc),0.f),
                       fmaxf(fmaf(v2,a,cc),0.f),fmaxf(fmaf(v3,a,cc),0.f));
  *(float4*)(outf+((size_t)b*128+o)*SS+s4)=r;
}

extern "C" void kernel_launch(void* const* d_in, const int* in_sizes, int n_in,
                              void* d_out, int out_size, void* d_ws, size_t ws_size,
                              hipStream_t stream){
  (void)in_sizes;(void)n_in;(void)out_size;(void)ws_size;
  const float* xyz =(const float*)d_in[0];
  const float* feat=(const float*)d_in[1];
  const float* w0=(const float*)d_in[2];  const float* g0=(const float*)d_in[4];  const float* be0=(const float*)d_in[5];
  const float* w1=(const float*)d_in[6];  const float* g1=(const float*)d_in[8];  const float* be1=(const float*)d_in[9];
  const float* w2=(const float*)d_in[10]; const float* g2=(const float*)d_in[12]; const float* be2=(const float*)d_in[13];
  const float* ww0=(const float*)d_in[14]; const float* wg0=(const float*)d_in[16]; const float* wbe0=(const float*)d_in[17];
  const float* ww1=(const float*)d_in[18]; const float* wg1=(const float*)d_in[20]; const float* wbe1=(const float*)d_in[21];
  const float* ww2=(const float*)d_in[22]; const float* wg2=(const float*)d_in[24]; const float* wbe2=(const float*)d_in[25];
  const float* lw=(const float*)d_in[26]; const float* lg=(const float*)d_in[28]; const float* lbe=(const float*)d_in[29];
  float* out=(float*)d_out;
  char* ws=(char*)d_ws;

  size_t cur=0;
  auto alloc=[&](size_t bytes)->size_t{ cur=(cur+255)&~(size_t)255; size_t o=cur; cur+=bytes; return o; };
  size_t o_stats=alloc(4096);
  size_t o_w0t =alloc(67*64*4);
  size_t o_w1t =alloc(64*64*4);
  size_t o_w2t =alloc(64*128*4);
  size_t o_wt0 =alloc(3*8*4);
  size_t o_wt1 =alloc(8*8*4);
  size_t o_wt2 =alloc(8*16*4);
  size_t o_fpsq=alloc((size_t)BB*SS*3*4);
  size_t o_kidx=alloc((size_t)PP*4);
  size_t o_ft  =alloc((size_t)BB*NN*64*4);
  size_t o_y0  =alloc((size_t)PP*64*2);
  size_t o_y1  =alloc((size_t)PP*64*2);
  size_t o_y2  =alloc((size_t)PP*128*2);
  size_t o_wl0 =alloc((size_t)PP*8*4);
  size_t o_wl1 =alloc((size_t)PP*8*4);
  size_t o_wl2 =alloc((size_t)PP*16*4);
  size_t o_agg =alloc((size_t)8192*2048*2);
  size_t o_lin =alloc((size_t)8192*128*4);

  float* statsf=(float*)(ws+o_stats);
  float* w0t=(float*)(ws+o_w0t); float* w1t=(float*)(ws+o_w1t); float* w2t=(float*)(ws+o_w2t);
  float* wt0=(float*)(ws+o_wt0); float* wt1=(float*)(ws+o_wt1); float* wt2=(float*)(ws+o_wt2);
  float* fpsq=(float*)(ws+o_fpsq); int* kidx=(int*)(ws+o_kidx);
  float* ft=(float*)(ws+o_ft);
  u16* y0=(u16*)(ws+o_y0); u16* y1=(u16*)(ws+o_y1); u16* y2=(u16*)(ws+o_y2);
  float* wl0=(float*)(ws+o_wl0); float* wl1=(float*)(ws+o_wl1); float* wl2=(float*)(ws+o_wl2);
  u16* agg=(u16*)(ws+o_agg); float* lin=(float*)(ws+o_lin);

  size_t knn_smem = (size_t)4*64*KSTR*4;             // 69632 B

  hipLaunchKernelGGL(k_prep,dim3(1),dim3(256),0,stream,w0,w1,w2,ww0,ww1,ww2,w0t,w1t,w2t,wt0,wt1,wt2,statsf);
  hipLaunchKernelGGL(k_fps,dim3(BB),dim3(512),0,stream,xyz,fpsq,out);
  hipLaunchKernelGGL(k_featT,dim3(512),dim3(256),0,stream,feat,ft);
  hipLaunchKernelGGL(k_knn,dim3(2048),dim3(256),knn_smem,stream,xyz,fpsq,kidx);
  hipLaunchKernelGGL(k_l0,dim3(PP/256),dim3(256),0,stream,xyz,ft,fpsq,kidx,w0t,wt0,y0,wl0);
  hipLaunchKernelGGL(k_stats2,dim3(1024),dim3(256),0,stream,y0,64,wl0,8,statsf+2*ST_Y0,statsf+2*ST_W0);
  hipLaunchKernelGGL(k_l1,dim3(PP/256),dim3(256),0,stream,y0,wl0,w1t,wt1,statsf,g0,be0,wg0,wbe0,y1,wl1);
  hipLaunchKernelGGL(k_stats2,dim3(1024),dim3(256),0,stream,y1,64,wl1,8,statsf+2*ST_Y1,statsf+2*ST_W1);
  hipLaunchKernelGGL(k_l2,dim3(PP/256),dim3(256),0,stream,y1,wl1,w2t,wt2,statsf,g1,be1,wg1,wbe1,y2,wl2);
  hipLaunchKernelGGL(k_stats2,dim3(1024),dim3(256),0,stream,y2,128,wl2,16,statsf+2*ST_Y2,statsf+2*ST_W2);
  hipLaunchKernelGGL(k_agg,dim3(8192),dim3(256),0,stream,y2,wl2,statsf,g2,be2,wg2,wbe2,agg);
  hipLaunchKernelGGL(k_lin,dim3(256),dim3(256),0,stream,agg,lw,lin,statsf+2*ST_LIN);
  hipLaunchKernelGGL(k_out,dim3(1024),dim3(256),0,stream,lin,statsf,lg,lbe,out+BB*3*SS);
}

// Round 7
// 1356.618 us; speedup vs baseline: 1.2426x; 1.2426x over previous
//
#include <hip/hip_runtime.h>
#include <hip/hip_bf16.h>

// PointConv SetAbstraction for MI355X. B=8,N=4096,S=1024,K=32,D=64.
#define BB 8
#define NN 4096
#define SS 1024
#define KK 32
#define PP (BB*SS*KK)   // 262144

typedef unsigned long long u64;
typedef unsigned int u32;
typedef unsigned short u16;
typedef float f32x2 __attribute__((ext_vector_type(2)));

// stats slots (each slot = 2 floats: sum, sumsq)
#define ST_Y0 0
#define ST_W0 64
#define ST_Y1 72
#define ST_W1 136
#define ST_Y2 144
#define ST_W2 272
#define ST_LIN 288
#define ST_TOTAL 416

static __device__ __forceinline__ float bf2f(u32 u){ return __uint_as_float(u<<16); }
static __device__ __forceinline__ u16 f2bf(float f){ u32 u=__float_as_uint(f); return (u16)((u + 0x7FFFu + ((u>>16)&1u))>>16); }

// packed fp32 math (bit-exact vs scalar: per-lane IEEE RN)
static __device__ __forceinline__ f32x2 pk_add(f32x2 a, f32x2 b){
  f32x2 d; asm("v_pk_add_f32 %0, %1, %2" : "=v"(d) : "v"(a), "v"(b)); return d;
}
static __device__ __forceinline__ f32x2 pk_mul(f32x2 a, f32x2 b){
  f32x2 d; asm("v_pk_mul_f32 %0, %1, %2" : "=v"(d) : "v"(a), "v"(b)); return d;
}

static __device__ __forceinline__ uint4 pack8(const float* v){
  uint4 r;
  r.x=(u32)f2bf(v[0])|((u32)f2bf(v[1])<<16);
  r.y=(u32)f2bf(v[2])|((u32)f2bf(v[3])<<16);
  r.z=(u32)f2bf(v[4])|((u32)f2bf(v[5])<<16);
  r.w=(u32)f2bf(v[6])|((u32)f2bf(v[7])<<16);
  return r;
}

// unpack 8 bf16 + affine + relu
static __device__ __forceinline__ void unp8_aff(uint4 r, const float* A, const float* C, int cb, float* o){
  o[0]=fmaxf(fmaf(bf2f(r.x&0xffffu),A[cb+0],C[cb+0]),0.f);
  o[1]=fmaxf(fmaf(bf2f(r.x>>16)    ,A[cb+1],C[cb+1]),0.f);
  o[2]=fmaxf(fmaf(bf2f(r.y&0xffffu),A[cb+2],C[cb+2]),0.f);
  o[3]=fmaxf(fmaf(bf2f(r.y>>16)    ,A[cb+3],C[cb+3]),0.f);
  o[4]=fmaxf(fmaf(bf2f(r.z&0xffffu),A[cb+4],C[cb+4]),0.f);
  o[5]=fmaxf(fmaf(bf2f(r.z>>16)    ,A[cb+5],C[cb+5]),0.f);
  o[6]=fmaxf(fmaf(bf2f(r.w&0xffffu),A[cb+6],C[cb+6]),0.f);
  o[7]=fmaxf(fmaf(bf2f(r.w>>16)    ,A[cb+7],C[cb+7]),0.f);
}

// ---------------- weight transpose prep (+ statsf zero-init) ----------------
__global__ void k_prep(const float* __restrict__ w0,const float* __restrict__ w1,const float* __restrict__ w2,
                       const float* __restrict__ ww0,const float* __restrict__ ww1,const float* __restrict__ ww2,
                       float* __restrict__ w0t,float* __restrict__ w1t,float* __restrict__ w2t,
                       float* __restrict__ wt0,float* __restrict__ wt1,float* __restrict__ wt2,
                       float* __restrict__ statsf){
  int t=threadIdx.x;
  for (int i=t;i<1024;i+=256) statsf[i]=0.f;
  for (int i=t;i<64*67;i+=256){ int o=i/67,k=i%67; w0t[k*64+o]=w0[i]; }
  for (int i=t;i<64*64;i+=256){ int o=i>>6,k=i&63; w1t[k*64+o]=w1[i]; }
  for (int i=t;i<128*64;i+=256){ int o=i>>6,k=i&63; w2t[k*128+o]=w2[i]; }
  for (int i=t;i<8*3;i+=256){ int o=i/3,k=i%3; wt0[k*8+o]=ww0[i]; }
  for (int i=t;i<8*8;i+=256){ int o=i>>3,k=i&7; wt1[k*8+o]=ww1[i]; }
  for (int i=t;i<16*8;i+=256){ int o=i>>3,k=i&7; wt2[k*16+o]=ww2[i]; }
}

// ---------------- FPS: round-5 structure; outputs buffered in LDS (no global stores in loop) ----------------
template<int CTRL, int RMASK>
static __device__ __forceinline__ u32 dppmax(u32 m){
  u32 t=(u32)__builtin_amdgcn_update_dpp(0, (int)m, CTRL, RMASK, 0xf, false);
  return t>m ? t : m;
}

__global__ __launch_bounds__(512) void k_fps(const float* __restrict__ xyz,
                                             float* __restrict__ fpsq, float* __restrict__ outx){
  __shared__ float X[NN], Y[NN], Z[NN];
  __shared__ float QX[SS], QY[SS], QZ[SS];
  __shared__ u64 red[2][8];
  int b=blockIdx.x, t=threadIdx.x;
  const float* xb=xyz+(size_t)b*3*NN;
  for (int i=t;i<NN;i+=512){ X[i]=xb[i]; Y[i]=xb[NN+i]; Z[i]=xb[2*NN+i]; }
  __syncthreads();
  f32x2 px[4],py[4],pz[4],dd[4];
  #pragma unroll
  for (int k=0;k<4;k++){
    int i=t*8+2*k;
    px[k].x=X[i]; px[k].y=X[i+1];
    py[k].x=Y[i]; py[k].y=Y[i+1];
    pz[k].x=Z[i]; pz[k].y=Z[i+1];
    dd[k].x=1e10f; dd[k].y=1e10f;
  }
  int wv=t>>6, ln=t&63;
  int far=0;
  for (int s=0;s<SS;s++){
    float fx=X[far], fy=Y[far], fz=Z[far];
    if (t==0){ QX[s]=fx; QY[s]=fy; QZ[s]=fz; }
    f32x2 nfx, nfy, nfz;
    nfx.x=-fx; nfx.y=-fx; nfy.x=-fy; nfy.y=-fy; nfz.x=-fz; nfz.y=-fz;
    #pragma unroll
    for (int k=0;k<4;k++){
      f32x2 dx=pk_add(px[k],nfx);      // == px - fx (IEEE: a-b = a+(-b))
      f32x2 xx=pk_mul(dx,dx);
      f32x2 dy=pk_add(py[k],nfy);
      f32x2 yy=pk_mul(dy,dy);
      f32x2 dz=pk_add(pz[k],nfz);
      f32x2 zz=pk_mul(dz,dz);
      f32x2 s1=pk_add(xx,yy);
      f32x2 d2=pk_add(s1,zz);          // ((dx^2+dy^2)+dz^2), ref order
      dd[k].x=fminf(dd[k].x,d2.x);
      dd[k].y=fminf(dd[k].y,d2.y);
    }
    // thread-local max tree (dd >= 0 -> uint compare == float compare)
    float m01=fmaxf(dd[0].x,dd[0].y), m23=fmaxf(dd[1].x,dd[1].y);
    float m45=fmaxf(dd[2].x,dd[2].y), m67=fmaxf(dd[3].x,dd[3].y);
    u32 m=__float_as_uint(fmaxf(fmaxf(m01,m23),fmaxf(m45,m67)));
    // row-wise DPP reduce, then SALU combine of the 4 row maxima
    m=dppmax<0x111,0xf>(m);
    m=dppmax<0x112,0xf>(m);
    m=dppmax<0x114,0xf>(m);
    m=dppmax<0x118,0xf>(m);
    u32 r15=(u32)__builtin_amdgcn_readlane((int)m,15);
    u32 r31=(u32)__builtin_amdgcn_readlane((int)m,31);
    u32 r47=(u32)__builtin_amdgcn_readlane((int)m,47);
    u32 r63=(u32)__builtin_amdgcn_readlane((int)m,63);
    u32 ab = r15>r31 ? r15 : r31;
    u32 cd = r47>r63 ? r47 : r63;
    u32 wmax = ab>cd ? ab : cd;
    // lowest local element achieving wmax
    int lj=8;
    if (__float_as_uint(dd[3].y)==wmax) lj=7;
    if (__float_as_uint(dd[3].x)==wmax) lj=6;
    if (__float_as_uint(dd[2].y)==wmax) lj=5;
    if (__float_as_uint(dd[2].x)==wmax) lj=4;
    if (__float_as_uint(dd[1].y)==wmax) lj=3;
    if (__float_as_uint(dd[1].x)==wmax) lj=2;
    if (__float_as_uint(dd[0].y)==wmax) lj=1;
    if (__float_as_uint(dd[0].x)==wmax) lj=0;
    u64 ball=__ballot(lj<8);
    u32 wl=(u32)__builtin_ctzll(ball);            // lowest lane == lowest index (contiguous order)
    int gi=t*8+lj;
    u32 widx=(u32)__builtin_amdgcn_readlane(gi,wl);
    int pb=s&1;
    if (ln==0) red[pb][wv]=((u64)wmax<<32)|(u32)(4095u-widx);
    __syncthreads();
    // keys are positive finite doubles (high word <= 0x7F7F....) -> f64 max == u64 max
    const double* rd=(const double*)&red[pb][0];
    double g=fmax(fmax(fmax(rd[0],rd[1]),fmax(rd[2],rd[3])),
                  fmax(fmax(rd[4],rd[5]),fmax(rd[6],rd[7])));
    far=4095-(int)(__double_as_longlong(g)&0xFFFull);
  }
  __syncthreads();
  // one-time dump of buffered outputs
  for (int i=t;i<SS;i+=512){
    float qx=QX[i], qy=QY[i], qz=QZ[i];
    float* q=&fpsq[((size_t)b*SS+i)*3]; q[0]=qx; q[1]=qy; q[2]=qz;
    outx[b*3*SS+i]=qx; outx[b*3*SS+SS+i]=qy; outx[b*3*SS+2*SS+i]=qz;
  }
}

// ---------------- feature transpose [B,64,N] -> [B,N,64] ----------------
__global__ __launch_bounds__(256) void k_featT(const float* __restrict__ f, float* __restrict__ ft){
  __shared__ float tile[64][65];
  int b=blockIdx.x>>6; int n0=(blockIdx.x&63)*64;
  const float* fb=f+(size_t)b*64*NN;
  int c0=threadIdx.x>>6, nn=threadIdx.x&63;
  #pragma unroll
  for (int it=0;it<16;it++){ int c=c0+it*4; tile[c][nn]=fb[(size_t)c*NN+n0+nn]; }
  __syncthreads();
  int cc=threadIdx.x&63, n1=threadIdx.x>>6;
  float* fo=ft+((size_t)b*NN+n0)*64;
  #pragma unroll
  for (int it=0;it<16;it++){ int n=n1+it*4; fo[(size_t)n*64+cc]=tile[cc][n]; }
}

// ---------------- KNN: top-32 of 4096 per query, one wave/query ----------------
#define KSTR 68
__global__ __launch_bounds__(256) void k_knn(const float* __restrict__ xyz, const float* __restrict__ fpsq,
                                             int* __restrict__ kidx){
  extern __shared__ char smem[];
  float* xs=(float*)smem;
  float* ys=xs+64*KSTR;
  float* zs=ys+64*KSTR;
  float* pn=zs+64*KSTR;
  int blk=blockIdx.x; int b=blk>>8; int s0=(blk&255)*4;
  const float* xb=xyz+(size_t)b*3*NN;
  for (int i=threadIdx.x;i<NN;i+=256){
    float x=xb[i],y=xb[NN+i],z=xb[2*NN+i];
    int slot=(i>>6)*KSTR+(i&63);
    xs[slot]=x; ys[slot]=y; zs[slot]=z;
    pn[slot]=__fadd_rn(__fadd_rn(__fmul_rn(x,x),__fmul_rn(y,y)),__fmul_rn(z,z));
  }
  __syncthreads();
  int wv=threadIdx.x>>6, ln=threadIdx.x&63;
  int s=s0+wv;
  const float* q=&fpsq[((size_t)b*SS+s)*3];
  float qx=q[0],qy=q[1],qz=q[2];
  float qn=__fadd_rn(__fadd_rn(__fmul_rn(qx,qx),__fmul_rn(qy,qy)),__fmul_rn(qz,qz));
  f32x2 qxx,qyy,qzz,qnn,mtwo;
  qxx.x=qx;qxx.y=qx; qyy.x=qy;qyy.y=qy; qzz.x=qz;qzz.y=qz; qnn.x=qn;qnn.y=qn;
  mtwo.x=-2.f; mtwo.y=-2.f;
  const float4* Xp=(const float4*)(xs+ln*KSTR);
  const float4* Yp=(const float4*)(ys+ln*KSTR);
  const float4* Zp=(const float4*)(zs+ln*KSTR);
  const float4* Pp=(const float4*)(pn+ln*KSTR);
  int base=ln*64;
  u64 v[64];
  #pragma unroll
  for (int g=0;g<16;g++){
    float4 x4=Xp[g], y4=Yp[g], z4=Zp[g], p4=Pp[g];
    #pragma unroll
    for (int h=0;h<2;h++){
      f32x2 px2,py2,pz2,pn2;
      if (h==0){ px2.x=x4.x;px2.y=x4.y; py2.x=y4.x;py2.y=y4.y; pz2.x=z4.x;pz2.y=z4.y; pn2.x=p4.x;pn2.y=p4.y; }
      else     { px2.x=x4.z;px2.y=x4.w; py2.x=y4.z;py2.y=y4.w; pz2.x=z4.z;pz2.y=z4.w; pn2.x=p4.z;pn2.y=p4.w; }
      f32x2 m1=pk_mul(qxx,px2);
      f32x2 mm=pk_mul(qyy,py2);
      f32x2 a1=pk_add(m1,mm);
      f32x2 m3=pk_mul(qzz,pz2);
      f32x2 dt=pk_add(a1,m3);           // (qx*px+qy*py)+qz*pz, ref order
      f32x2 qp=pk_add(qnn,pn2);         // qn+pn
      f32x2 nd=pk_mul(dt,mtwo);         // -(2*dt) bit-exact
      f32x2 d2=pk_add(qp,nd);           // (qn+pn)-2*dt
      #pragma unroll
      for (int e=0;e<2;e++){
        u32 bu=__float_as_uint(e?d2.y:d2.x);
        bu = ((int)bu<0)? ~bu : (bu|0x80000000u);
        v[g*4+h*2+e]=((u64)bu<<32)|(u32)(base+g*4+h*2+e);
      }
    }
  }
  u64 cand[8];
  #pragma unroll
  for (int gg=0;gg<8;gg++){
    u64 c=v[gg*8];
    #pragma unroll
    for (int j=1;j<8;j++){ u64 x=v[gg*8+j]; c = x<c?x:c; }
    cand[gg]=c;
  }
  u64 best=cand[0];
  #pragma unroll
  for (int gg=1;gg<8;gg++){ u64 x=cand[gg]; best = x<best?x:best; }
  int my=0;
  #pragma unroll 1
  for (int r=0;r<KK;r++){
    u64 w=best;
    #pragma unroll
    for (int m=1;m<64;m<<=1){ u64 o=__shfl_xor(w,m,64); w = o<w?o:w; }
    if (ln==r) my=(int)(w&0xFFFull);
    if (best==w){
      #pragma unroll
      for (int gg=0;gg<8;gg++){
        if (cand[gg]==w){
          u64 c=~0ull;
          #pragma unroll
          for (int j=0;j<8;j++){ u64 x=v[gg*8+j]; x = x>w ? x : ~0ull; c = x<c?x:c; }
          cand[gg]=c;
        }
      }
      u64 nb=cand[0];
      #pragma unroll
      for (int gg=1;gg<8;gg++){ u64 x=cand[gg]; nb = x<nb?x:nb; }
      best=nb;
    }
  }
  if (ln<KK) kidx[(((size_t)b*SS+s)<<5)+ln]=my;
}

// ---------------- layer 0: gather + 67->64 + wnet 3->8 ----------------
__global__ __launch_bounds__(256) void k_l0(const float* __restrict__ xyz, const float* __restrict__ ft,
    const float* __restrict__ fpsq, const int* __restrict__ kidx,
    const float* __restrict__ w0t, const float* __restrict__ wt0,
    u16* __restrict__ y0, float* __restrict__ wl0){
  int p=blockIdx.x*256+threadIdx.x;
  int b=p>>15;
  int site=p>>5;
  int j=kidx[p];
  const float* xb=xyz+(size_t)b*3*NN;
  const float* q=fpsq+(size_t)site*3;
  float gx=xb[j]-q[0], gy=xb[NN+j]-q[1], gz=xb[2*NN+j]-q[2];
  float acc[64];
  #pragma unroll
  for (int c=0;c<64;c++) acc[c]=fmaf(gx,w0t[c],fmaf(gy,w0t[64+c],gz*w0t[128+c]));
  const float4* fr=(const float4*)(ft+((size_t)b*NN+j)*64);
  #pragma unroll 1
  for (int kb=0;kb<4;kb++){
    float4 r0=fr[kb*4+0], r1=fr[kb*4+1], r2=fr[kb*4+2], r3=fr[kb*4+3];
    float ch[16]={r0.x,r0.y,r0.z,r0.w,r1.x,r1.y,r1.z,r1.w,r2.x,r2.y,r2.z,r2.w,r3.x,r3.y,r3.z,r3.w};
    const float* wb=w0t+(3+kb*16)*64;
    #pragma unroll
    for (int kk=0;kk<16;kk++){
      #pragma unroll
      for (int c=0;c<64;c++) acc[c]=fmaf(ch[kk],wb[kk*64+c],acc[c]);
    }
  }
  u16* yr=y0+(size_t)p*64;
  #pragma unroll
  for (int c8=0;c8<8;c8++) ((uint4*)yr)[c8]=pack8(&acc[c8*8]);
  float wa[8];
  #pragma unroll
  for (int o=0;o<8;o++) wa[o]=fmaf(gx,wt0[o],fmaf(gy,wt0[8+o],gz*wt0[16+o]));
  float4* wr=(float4*)(wl0+(size_t)p*8);
  wr[0]=make_float4(wa[0],wa[1],wa[2],wa[3]);
  wr[1]=make_float4(wa[4],wa[5],wa[6],wa[7]);
}

// ---------------- paired column stats: y (bf16) + w (f32) in one dispatch ----------------
#define STATS_YB 896
__global__ __launch_bounds__(256) void k_stats2(const u16* __restrict__ yb, int nchy,
                                                const float* __restrict__ wb, int nchw,
                                                float* __restrict__ outy, float* __restrict__ outw){
  __shared__ float lds[4][256];   // [wave][0..127]=sum, [128..255]=sumsq
  int t=threadIdx.x; int wv=t>>6, ln=t&63;
  float s[8]={0,0,0,0,0,0,0,0}, q[8]={0,0,0,0,0,0,0,0};
  int isbf = blockIdx.x < STATS_YB;
  int bid  = isbf ? blockIdx.x : (blockIdx.x - STATS_YB);
  int nb   = isbf ? STATS_YB : (gridDim.x - STATS_YB);
  int nch  = isbf ? nchy : nchw;
  float* out = isbf ? outy : outw;
  int E = isbf ? 8 : 4;
  int L = nch / E;
  int lir=t&(L-1);
  int rib=t/L;
  int rpb=256/L;
  int r=bid*rpb+rib;
  int rstride=nb*rpb;
  if (isbf){
    const u16* u=yb;
    for (; r<PP; r+=rstride){
      uint4 raw=*(const uint4*)(u+(size_t)r*nch+lir*8);
      float v0=bf2f(raw.x&0xffffu), v1=bf2f(raw.x>>16);
      float v2=bf2f(raw.y&0xffffu), v3=bf2f(raw.y>>16);
      float v4=bf2f(raw.z&0xffffu), v5=bf2f(raw.z>>16);
      float v6=bf2f(raw.w&0xffffu), v7=bf2f(raw.w>>16);
      s[0]+=v0; q[0]=fmaf(v0,v0,q[0]);
      s[1]+=v1; q[1]=fmaf(v1,v1,q[1]);
      s[2]+=v2; q[2]=fmaf(v2,v2,q[2]);
      s[3]+=v3; q[3]=fmaf(v3,v3,q[3]);
      s[4]+=v4; q[4]=fmaf(v4,v4,q[4]);
      s[5]+=v5; q[5]=fmaf(v5,v5,q[5]);
      s[6]+=v6; q[6]=fmaf(v6,v6,q[6]);
      s[7]+=v7; q[7]=fmaf(v7,v7,q[7]);
    }
  } else {
    const float* f=wb;
    for (; r<PP; r+=rstride){
      float4 v=*(const float4*)(f+(size_t)r*nch+lir*4);
      s[0]+=v.x; q[0]=fmaf(v.x,v.x,q[0]);
      s[1]+=v.y; q[1]=fmaf(v.y,v.y,q[1]);
      s[2]+=v.z; q[2]=fmaf(v.z,v.z,q[2]);
      s[3]+=v.w; q[3]=fmaf(v.w,v.w,q[3]);
    }
  }
  for (int m=L; m<64; m<<=1){
    #pragma unroll
    for (int e=0;e<8;e++){
      s[e]+=__shfl_xor(s[e],m,64);
      q[e]+=__shfl_xor(q[e],m,64);
    }
  }
  if (ln<L){
    int cb=ln*E;
    #pragma unroll
    for (int e=0;e<8;e++){
      if (e<E){ lds[wv][cb+e]=s[e]; lds[wv][128+cb+e]=q[e]; }
    }
  }
  __syncthreads();
  if (t<nch){
    float S=lds[0][t]+lds[1][t]+lds[2][t]+lds[3][t];
    float Q=lds[0][128+t]+lds[1][128+t]+lds[2][128+t]+lds[3][128+t];
    atomicAdd(&out[2*t],S); atomicAdd(&out[2*t+1],Q);
  }
}

// ---------------- layer 1: BN0+relu -> 64->64 ; wnet BN+relu 8->8 ----------------
__global__ __launch_bounds__(256) void k_l1(const u16* __restrict__ y0, const float* __restrict__ wl0,
    const float* __restrict__ w1t, const float* __restrict__ wt1,
    const float* __restrict__ statsf,
    const float* __restrict__ g0v, const float* __restrict__ be0v,
    const float* __restrict__ wg0v, const float* __restrict__ wbe0v,
    u16* __restrict__ y1, float* __restrict__ wl1){
  __shared__ float A0[64],C0[64],AW[8],CW[8];
  int t=threadIdx.x;
  if (t<64){
    float sm=statsf[(ST_Y0+t)*2], sq=statsf[(ST_Y0+t)*2+1];
    float mean=sm*(1.f/PP), var=fmaxf(sq*(1.f/PP)-mean*mean,0.f);
    float a=g0v[t]*rsqrtf(var+1e-5f); A0[t]=a; C0[t]=be0v[t]-mean*a;
  } else if (t<72){
    int c=t-64;
    float sm=statsf[(ST_W0+c)*2], sq=statsf[(ST_W0+c)*2+1];
    float mean=sm*(1.f/PP), var=fmaxf(sq*(1.f/PP)-mean*mean,0.f);
    float a=wg0v[c]*rsqrtf(var+1e-5f); AW[c]=a; CW[c]=wbe0v[c]-mean*a;
  }
  __syncthreads();
  int p=blockIdx.x*256+t;
  const uint4* yr=(const uint4*)(y0+(size_t)p*64);
  float acc[64];
  #pragma unroll
  for (int c=0;c<64;c++) acc[c]=0.f;
  #pragma unroll 1
  for (int kb=0;kb<4;kb++){
    uint4 r0=yr[kb*2], r1=yr[kb*2+1];
    float ch[16];
    unp8_aff(r0,A0,C0,kb*16,ch);
    unp8_aff(r1,A0,C0,kb*16+8,ch+8);
    const float* wb=w1t+kb*16*64;
    #pragma unroll
    for (int kk=0;kk<16;kk++){
      #pragma unroll
      for (int c=0;c<64;c++) acc[c]=fmaf(ch[kk],wb[kk*64+c],acc[c]);
    }
  }
  u16* yo=y1+(size_t)p*64;
  #pragma unroll
  for (int c8=0;c8<8;c8++) ((uint4*)yo)[c8]=pack8(&acc[c8*8]);
  const float4* wvp=(const float4*)(wl0+(size_t)p*8);
  float4 v0=wvp[0], v1=wvp[1];
  float wi[8]={v0.x,v0.y,v0.z,v0.w,v1.x,v1.y,v1.z,v1.w};
  float wo[8];
  #pragma unroll
  for (int o=0;o<8;o++) wo[o]=0.f;
  #pragma unroll
  for (int k=0;k<8;k++){
    float xr=fmaxf(fmaf(wi[k],AW[k],CW[k]),0.f);
    #pragma unroll
    for (int o=0;o<8;o++) wo[o]=fmaf(xr,wt1[k*8+o],wo[o]);
  }
  float4* wr=(float4*)(wl1+(size_t)p*8);
  wr[0]=make_float4(wo[0],wo[1],wo[2],wo[3]);
  wr[1]=make_float4(wo[4],wo[5],wo[6],wo[7]);
}

// ---------------- layer 2: BN1+relu -> 64->128 ; wnet BN+relu 8->16 ----------------
__global__ __launch_bounds__(256) void k_l2(const u16* __restrict__ y1, const float* __restrict__ wl1,
    const float* __restrict__ w2t, const float* __restrict__ wt2,
    const float* __restrict__ statsf,
    const float* __restrict__ g1v, const float* __restrict__ be1v,
    const float* __restrict__ wg1v, const float* __restrict__ wbe1v,
    u16* __restrict__ y2, float* __restrict__ wl2){
  __shared__ float A1[64],C1[64],AW[8],CW[8];
  int t=threadIdx.x;
  if (t<64){
    float sm=statsf[(ST_Y1+t)*2], sq=statsf[(ST_Y1+t)*2+1];
    float mean=sm*(1.f/PP), var=fmaxf(sq*(1.f/PP)-mean*mean,0.f);
    float a=g1v[t]*rsqrtf(var+1e-5f); A1[t]=a; C1[t]=be1v[t]-mean*a;
  } else if (t<72){
    int c=t-64;
    float sm=statsf[(ST_W1+c)*2], sq=statsf[(ST_W1+c)*2+1];
    float mean=sm*(1.f/PP), var=fmaxf(sq*(1.f/PP)-mean*mean,0.f);
    float a=wg1v[c]*rsqrtf(var+1e-5f); AW[c]=a; CW[c]=wbe1v[c]-mean*a;
  }
  __syncthreads();
  int p=blockIdx.x*256+t;
  const uint4* yr=(const uint4*)(y1+(size_t)p*64);
  #pragma unroll 1
  for (int h=0;h<2;h++){
    float acc[64];
    #pragma unroll
    for (int c=0;c<64;c++) acc[c]=0.f;
    #pragma unroll 1
    for (int kb=0;kb<4;kb++){
      uint4 r0=yr[kb*2], r1=yr[kb*2+1];
      float ch[16];
      unp8_aff(r0,A1,C1,kb*16,ch);
      unp8_aff(r1,A1,C1,kb*16+8,ch+8);
      const float* wb=w2t+(size_t)kb*16*128+h*64;
      #pragma unroll
      for (int kk=0;kk<16;kk++){
        #pragma unroll
        for (int c=0;c<64;c++) acc[c]=fmaf(ch[kk],wb[kk*128+c],acc[c]);
      }
    }
    u16* yo=y2+(size_t)p*128+h*64;
    #pragma unroll
    for (int c8=0;c8<8;c8++) ((uint4*)yo)[c8]=pack8(&acc[c8*8]);
  }
  const float4* wvp=(const float4*)(wl1+(size_t)p*8);
  float4 v0=wvp[0], v1=wvp[1];
  float wi[8]={v0.x,v0.y,v0.z,v0.w,v1.x,v1.y,v1.z,v1.w};
  float wo[16];
  #pragma unroll
  for (int o=0;o<16;o++) wo[o]=0.f;
  #pragma unroll
  for (int k=0;k<8;k++){
    float xr=fmaxf(fmaf(wi[k],AW[k],CW[k]),0.f);
    #pragma unroll
    for (int o=0;o<16;o++) wo[o]=fmaf(xr,wt2[k*16+o],wo[o]);
  }
  float4* wr=(float4*)(wl2+(size_t)p*16);
  wr[0]=make_float4(wo[0],wo[1],wo[2],wo[3]);
  wr[1]=make_float4(wo[4],wo[5],wo[6],wo[7]);
  wr[2]=make_float4(wo[8],wo[9],wo[10],wo[11]);
  wr[3]=make_float4(wo[12],wo[13],wo[14],wo[15]);
}

// ---------------- agg: per site, BN2+relu both, outer-product pooled over k ----------------
__global__ __launch_bounds__(256) void k_agg(const u16* __restrict__ y2, const float* __restrict__ wl2,
    const float* __restrict__ statsf,
    const float* __restrict__ g2v, const float* __restrict__ be2v,
    const float* __restrict__ wg2v, const float* __restrict__ wbe2v,
    u16* __restrict__ agg){
  __shared__ float A2[128],C2[128],AW[16],CW[16];
  __shared__ float nf[32*128];
  __shared__ float wt[32*16];
  int site=blockIdx.x; int t=threadIdx.x;
  if (t<128){
    float sm=statsf[(ST_Y2+t)*2], sq=statsf[(ST_Y2+t)*2+1];
    float mean=sm*(1.f/PP), var=fmaxf(sq*(1.f/PP)-mean*mean,0.f);
    float a=g2v[t]*rsqrtf(var+1e-5f); A2[t]=a; C2[t]=be2v[t]-mean*a;
  } else if (t<144){
    int c=t-128;
    float sm=statsf[(ST_W2+c)*2], sq=statsf[(ST_W2+c)*2+1];
    float mean=sm*(1.f/PP), var=fmaxf(sq*(1.f/PP)-mean*mean,0.f);
    float a=wg2v[c]*rsqrtf(var+1e-5f); AW[c]=a; CW[c]=wbe2v[c]-mean*a;
  }
  __syncthreads();
  const uint4* src=(const uint4*)(y2+(size_t)site*32*128);
  #pragma unroll
  for (int it=0;it<2;it++){
    int idx=t+it*256;
    uint4 r=src[idx];
    int base=(idx*8)&127; int kq=(idx*8)>>7;
    unp8_aff(r,A2,C2,base,&nf[kq*128+base]);
  }
  #pragma unroll
  for (int it=0;it<2;it++){
    int i=t+it*256;
    float x=wl2[(size_t)site*512+i]; int c=i&15;
    wt[i]=fmaxf(fmaf(x,AW[c],CW[c]),0.f);
  }
  __syncthreads();
  int d=t>>1, cb=(t&1)*8;
  float acc[8];
  #pragma unroll
  for (int e=0;e<8;e++) acc[e]=0.f;
  #pragma unroll 4
  for (int kq=0;kq<32;kq++){
    float nv=nf[kq*128+d];
    #pragma unroll
    for (int e=0;e<8;e++) acc[e]=fmaf(nv,wt[kq*16+cb+e],acc[e]);
  }
  ((uint4*)(agg+(size_t)site*2048))[t]=pack8(acc);
}

// ---------------- linear: [8192 x 2048] @ lw^T -> [8192 x 128], fused lin-stats ----------------
__global__ __launch_bounds__(256) void k_lin(const u16* __restrict__ agg, const float* __restrict__ lw,
                                             float* __restrict__ lin, float* __restrict__ outst){
  __shared__ float As[32][33];
  __shared__ float Bs[32][128];
  __shared__ float stS[8][132], stQ[8][132];
  int s0=blockIdx.x*32; int t=threadIdx.x;
  int tx=t&31, ty=t>>5;
  float acc[4][4];
  #pragma unroll
  for (int i=0;i<4;i++){
    #pragma unroll
    for (int jj=0;jj<4;jj++) acc[i][jj]=0.f;
  }
  for (int kb=0;kb<2048;kb+=32){
    {
      int row=t>>3, kc=(t&7)*4;
      uint2 raw=*(const uint2*)(agg+((size_t)(s0+row))*2048+kb+kc);
      As[row][kc  ]=bf2f(raw.x&0xffffu); As[row][kc+1]=bf2f(raw.x>>16);
      As[row][kc+2]=bf2f(raw.y&0xffffu); As[row][kc+3]=bf2f(raw.y>>16);
    }
    {
      int o=t>>1, ks=(t&1)*16;
      const float* lr=lw+(size_t)o*2048+kb+ks;
      #pragma unroll
      for (int i=0;i<16;i+=4){
        float4 r=*(const float4*)(lr+i);
        Bs[ks+i][o]=r.x; Bs[ks+i+1][o]=r.y; Bs[ks+i+2][o]=r.z; Bs[ks+i+3][o]=r.w;
      }
    }
    __syncthreads();
    #pragma unroll 8
    for (int kk=0;kk<32;kk++){
      float av[4];
      #pragma unroll
      for (int i=0;i<4;i++) av[i]=As[ty*4+i][kk];
      float4 bv=*(const float4*)(&Bs[kk][tx*4]);
      #pragma unroll
      for (int i=0;i<4;i++){
        acc[i][0]=fmaf(av[i],bv.x,acc[i][0]);
        acc[i][1]=fmaf(av[i],bv.y,acc[i][1]);
        acc[i][2]=fmaf(av[i],bv.z,acc[i][2]);
        acc[i][3]=fmaf(av[i],bv.w,acc[i][3]);
      }
    }
    __syncthreads();
  }
  #pragma unroll
  for (int i=0;i<4;i++){
    float4 o4=make_float4(acc[i][0],acc[i][1],acc[i][2],acc[i][3]);
    *(float4*)(lin+((size_t)(s0+ty*4+i))*128+tx*4)=o4;
  }
  // fused per-block column stats over the 32 rows this block produced
  #pragma unroll
  for (int jj=0;jj<4;jj++){
    float a0=acc[0][jj],a1=acc[1][jj],a2=acc[2][jj],a3=acc[3][jj];
    stS[ty][tx*4+jj]=(a0+a1)+(a2+a3);
    stQ[ty][tx*4+jj]=fmaf(a3,a3,fmaf(a2,a2,fmaf(a1,a1,a0*a0)));
  }
  __syncthreads();
  if (t<128){
    float S=0.f,Q=0.f;
    #pragma unroll
    for (int k=0;k<8;k++){ S+=stS[k][t]; Q+=stQ[k][t]; }
    atomicAdd(&outst[2*t],S); atomicAdd(&outst[2*t+1],Q);
  }
}

// ---------------- final BN + relu + transpose -> out [B,128,S] ----------------
__global__ __launch_bounds__(256) void k_out(const float* __restrict__ lin, const float* __restrict__ statsf,
    const float* __restrict__ lg, const float* __restrict__ lbe, float* __restrict__ outf){
  int t=blockIdx.x*256+threadIdx.x;  // 262144 = 8*128*256
  int s4=(t&255)*4; int o=(t>>8)&127; int b=t>>15;
  float sm=statsf[(ST_LIN+o)*2], sq=statsf[(ST_LIN+o)*2+1];
  float mean=sm*(1.f/8192.f), var=fmaxf(sq*(1.f/8192.f)-mean*mean,0.f);
  float a=lg[o]*rsqrtf(var+1e-5f), cc=lbe[o]-mean*a;
  float v0=lin[((size_t)b*SS+s4+0)*128+o];
  float v1=lin[((size_t)b*SS+s4+1)*128+o];
  float v2=lin[((size_t)b*SS+s4+2)*128+o];
  float v3=lin[((size_t)b*SS+s4+3)*128+o];
  float4 r=make_float4(fmaxf(fmaf(v0,a,cc),0.f),fmaxf(fmaf(v1,a,cc),0.f),
                       fmaxf(fmaf(v2,a,cc),0.f),fmaxf(fmaf(v3,a,cc),0.f));
  *(float4*)(outf+((size_t)b*128+o)*SS+s4)=r;
}

extern "C" void kernel_launch(void* const* d_in, const int* in_sizes, int n_in,
                              void* d_out, int out_size, void* d_ws, size_t ws_size,
                              hipStream_t stream){
  (void)in_sizes;(void)n_in;(void)out_size;(void)ws_size;
  const float* xyz =(const float*)d_in[0];
  const float* feat=(const float*)d_in[1];
  const float* w0=(const float*)d_in[2];  const float* g0=(const float*)d_in[4];  const float* be0=(const float*)d_in[5];
  const float* w1=(const float*)d_in[6];  const float* g1=(const float*)d_in[8];  const float* be1=(const float*)d_in[9];
  const float* w2=(const float*)d_in[10]; const float* g2=(const float*)d_in[12]; const float* be2=(const float*)d_in[13];
  const float* ww0=(const float*)d_in[14]; const float* wg0=(const float*)d_in[16]; const float* wbe0=(const float*)d_in[17];
  const float* ww1=(const float*)d_in[18]; const float* wg1=(const float*)d_in[20]; const float* wbe1=(const float*)d_in[21];
  const float* ww2=(const float*)d_in[22]; const float* wg2=(const float*)d_in[24]; const float* wbe2=(const float*)d_in[25];
  const float* lw=(const float*)d_in[26]; const float* lg=(const float*)d_in[28]; const float* lbe=(const float*)d_in[29];
  float* out=(float*)d_out;
  char* ws=(char*)d_ws;

  size_t cur=0;
  auto alloc=[&](size_t bytes)->size_t{ cur=(cur+255)&~(size_t)255; size_t o=cur; cur+=bytes; return o; };
  size_t o_stats=alloc(4096);
  size_t o_w0t =alloc(67*64*4);
  size_t o_w1t =alloc(64*64*4);
  size_t o_w2t =alloc(64*128*4);
  size_t o_wt0 =alloc(3*8*4);
  size_t o_wt1 =alloc(8*8*4);
  size_t o_wt2 =alloc(8*16*4);
  size_t o_fpsq=alloc((size_t)BB*SS*3*4);
  size_t o_kidx=alloc((size_t)PP*4);
  size_t o_ft  =alloc((size_t)BB*NN*64*4);
  size_t o_y0  =alloc((size_t)PP*64*2);
  size_t o_y1  =alloc((size_t)PP*64*2);
  size_t o_y2  =alloc((size_t)PP*128*2);
  size_t o_wl0 =alloc((size_t)PP*8*4);
  size_t o_wl1 =alloc((size_t)PP*8*4);
  size_t o_wl2 =alloc((size_t)PP*16*4);
  size_t o_agg =alloc((size_t)8192*2048*2);
  size_t o_lin =alloc((size_t)8192*128*4);

  float* statsf=(float*)(ws+o_stats);
  float* w0t=(float*)(ws+o_w0t); float* w1t=(float*)(ws+o_w1t); float* w2t=(float*)(ws+o_w2t);
  float* wt0=(float*)(ws+o_wt0); float* wt1=(float*)(ws+o_wt1); float* wt2=(float*)(ws+o_wt2);
  float* fpsq=(float*)(ws+o_fpsq); int* kidx=(int*)(ws+o_kidx);
  float* ft=(float*)(ws+o_ft);
  u16* y0=(u16*)(ws+o_y0); u16* y1=(u16*)(ws+o_y1); u16* y2=(u16*)(ws+o_y2);
  float* wl0=(float*)(ws+o_wl0); float* wl1=(float*)(ws+o_wl1); float* wl2=(float*)(ws+o_wl2);
  u16* agg=(u16*)(ws+o_agg); float* lin=(float*)(ws+o_lin);

  size_t knn_smem = (size_t)4*64*KSTR*4;             // 69632 B

  hipLaunchKernelGGL(k_prep,dim3(1),dim3(256),0,stream,w0,w1,w2,ww0,ww1,ww2,w0t,w1t,w2t,wt0,wt1,wt2,statsf);
  hipLaunchKernelGGL(k_fps,dim3(BB),dim3(512),0,stream,xyz,fpsq,out);
  hipLaunchKernelGGL(k_featT,dim3(512),dim3(256),0,stream,feat,ft);
  hipLaunchKernelGGL(k_knn,dim3(2048),dim3(256),knn_smem,stream,xyz,fpsq,kidx);
  hipLaunchKernelGGL(k_l0,dim3(PP/256),dim3(256),0,stream,xyz,ft,fpsq,kidx,w0t,wt0,y0,wl0);
  hipLaunchKernelGGL(k_stats2,dim3(1024),dim3(256),0,stream,y0,64,wl0,8,statsf+2*ST_Y0,statsf+2*ST_W0);
  hipLaunchKernelGGL(k_l1,dim3(PP/256),dim3(256),0,stream,y0,wl0,w1t,wt1,statsf,g0,be0,wg0,wbe0,y1,wl1);
  hipLaunchKernelGGL(k_stats2,dim3(1024),dim3(256),0,stream,y1,64,wl1,8,statsf+2*ST_Y1,statsf+2*ST_W1);
  hipLaunchKernelGGL(k_l2,dim3(PP/256),dim3(256),0,stream,y1,wl1,w2t,wt2,statsf,g1,be1,wg1,wbe1,y2,wl2);
  hipLaunchKernelGGL(k_stats2,dim3(1024),dim3(256),0,stream,y2,128,wl2,16,statsf+2*ST_Y2,statsf+2*ST_W2);
  hipLaunchKernelGGL(k_agg,dim3(8192),dim3(256),0,stream,y2,wl2,statsf,g2,be2,wg2,wbe2,agg);
  hipLaunchKernelGGL(k_lin,dim3(256),dim3(256),0,stream,agg,lw,lin,statsf+2*ST_LIN);
  hipLaunchKernelGGL(k_out,dim3(1024),dim3(256),0,stream,lin,statsf,lg,lbe,out+BB*3*SS);
}

// Round 8
// 1308.285 us; speedup vs baseline: 1.2886x; 1.0369x over previous
//
#include <hip/hip_runtime.h>
#include <hip/hip_bf16.h>

// PointConv SetAbstraction for MI355X. B=8,N=4096,S=1024,K=32,D=64.
#define BB 8
#define NN 4096
#define SS 1024
#define KK 32
#define PP (BB*SS*KK)   // 262144

typedef unsigned long long u64;
typedef unsigned int u32;
typedef unsigned short u16;
typedef float f32x2 __attribute__((ext_vector_type(2)));

// stats slots (each slot = 2 floats: sum, sumsq)
#define ST_Y0 0
#define ST_W0 64
#define ST_Y1 72
#define ST_W1 136
#define ST_Y2 144
#define ST_W2 272
#define ST_LIN 288

static __device__ __forceinline__ float bf2f(u32 u){ return __uint_as_float(u<<16); }
static __device__ __forceinline__ u16 f2bf(float f){ u32 u=__float_as_uint(f); return (u16)((u + 0x7FFFu + ((u>>16)&1u))>>16); }

// packed fp32 math (bit-exact vs scalar: per-lane IEEE RN)
static __device__ __forceinline__ f32x2 pk_add(f32x2 a, f32x2 b){
  f32x2 d; asm("v_pk_add_f32 %0, %1, %2" : "=v"(d) : "v"(a), "v"(b)); return d;
}
static __device__ __forceinline__ f32x2 pk_mul(f32x2 a, f32x2 b){
  f32x2 d; asm("v_pk_mul_f32 %0, %1, %2" : "=v"(d) : "v"(a), "v"(b)); return d;
}

static __device__ __forceinline__ uint4 pack8(const float* v){
  uint4 r;
  r.x=(u32)f2bf(v[0])|((u32)f2bf(v[1])<<16);
  r.y=(u32)f2bf(v[2])|((u32)f2bf(v[3])<<16);
  r.z=(u32)f2bf(v[4])|((u32)f2bf(v[5])<<16);
  r.w=(u32)f2bf(v[6])|((u32)f2bf(v[7])<<16);
  return r;
}

// unpack 8 bf16 + affine + relu
static __device__ __forceinline__ void unp8_aff(uint4 r, const float* A, const float* C, int cb, float* o){
  o[0]=fmaxf(fmaf(bf2f(r.x&0xffffu),A[cb+0],C[cb+0]),0.f);
  o[1]=fmaxf(fmaf(bf2f(r.x>>16)    ,A[cb+1],C[cb+1]),0.f);
  o[2]=fmaxf(fmaf(bf2f(r.y&0xffffu),A[cb+2],C[cb+2]),0.f);
  o[3]=fmaxf(fmaf(bf2f(r.y>>16)    ,A[cb+3],C[cb+3]),0.f);
  o[4]=fmaxf(fmaf(bf2f(r.z&0xffffu),A[cb+4],C[cb+4]),0.f);
  o[5]=fmaxf(fmaf(bf2f(r.z>>16)    ,A[cb+5],C[cb+5]),0.f);
  o[6]=fmaxf(fmaf(bf2f(r.w&0xffffu),A[cb+6],C[cb+6]),0.f);
  o[7]=fmaxf(fmaf(bf2f(r.w>>16)    ,A[cb+7],C[cb+7]),0.f);
}

// DPP helpers
template<int CTRL, int RMASK>
static __device__ __forceinline__ u32 dppmax(u32 m){
  u32 t=(u32)__builtin_amdgcn_update_dpp(0, (int)m, CTRL, RMASK, 0xf, false);
  return t>m ? t : m;
}
template<int CTRL, int RMASK>
static __device__ __forceinline__ float dppadd1(float v){
  float t=__uint_as_float((u32)__builtin_amdgcn_update_dpp(0,(int)__float_as_uint(v),CTRL,RMASK,0xf,false));
  return v+t;
}
// full-wave f32 sum; total lands in lane 63
static __device__ __forceinline__ float dppsum(float v){
  v=dppadd1<0x111,0xf>(v);
  v=dppadd1<0x112,0xf>(v);
  v=dppadd1<0x114,0xf>(v);
  v=dppadd1<0x118,0xf>(v);
  v=dppadd1<0x142,0xa>(v);
  v=dppadd1<0x143,0xc>(v);
  return v;
}
static __device__ __forceinline__ float rl63(float v){
  return __uint_as_float((u32)__builtin_amdgcn_readlane((int)__float_as_uint(v),63));
}

// ---------------- feature transpose [B,64,N] -> [B,N,64]; block 512 = weight prep ----------------
__global__ __launch_bounds__(256) void k_featT(const float* __restrict__ f, float* __restrict__ ft,
    const float* __restrict__ w0,const float* __restrict__ w1,const float* __restrict__ w2,
    const float* __restrict__ ww0,const float* __restrict__ ww1,const float* __restrict__ ww2,
    float* __restrict__ w0t,float* __restrict__ w1t,float* __restrict__ w2t,
    float* __restrict__ wt0,float* __restrict__ wt1,float* __restrict__ wt2,
    float* __restrict__ statsf){
  __shared__ float tile[64][65];
  if (blockIdx.x==512){
    int t=threadIdx.x;
    for (int i=t;i<1024;i+=256) statsf[i]=0.f;
    for (int i=t;i<64*67;i+=256){ int o=i/67,k=i%67; w0t[k*64+o]=w0[i]; }
    for (int i=t;i<64*64;i+=256){ int o=i>>6,k=i&63; w1t[k*64+o]=w1[i]; }
    for (int i=t;i<128*64;i+=256){ int o=i>>6,k=i&63; w2t[k*128+o]=w2[i]; }
    for (int i=t;i<8*3;i+=256){ int o=i/3,k=i%3; wt0[k*8+o]=ww0[i]; }
    for (int i=t;i<8*8;i+=256){ int o=i>>3,k=i&7; wt1[k*8+o]=ww1[i]; }
    for (int i=t;i<16*8;i+=256){ int o=i>>3,k=i&7; wt2[k*16+o]=ww2[i]; }
    return;
  }
  int b=blockIdx.x>>6; int n0=(blockIdx.x&63)*64;
  const float* fb=f+(size_t)b*64*NN;
  int c0=threadIdx.x>>6, nn=threadIdx.x&63;
  #pragma unroll
  for (int it=0;it<16;it++){ int c=c0+it*4; tile[c][nn]=fb[(size_t)c*NN+n0+nn]; }
  __syncthreads();
  int cc=threadIdx.x&63, n1=threadIdx.x>>6;
  float* fo=ft+((size_t)b*NN+n0)*64;
  #pragma unroll
  for (int it=0;it<16;it++){ int n=n1+it*4; fo[(size_t)n*64+cc]=tile[cc][n]; }
}

// ---------------- FPS (round-5/7 proven structure) ----------------
__global__ __launch_bounds__(512) void k_fps(const float* __restrict__ xyz,
                                             float* __restrict__ fpsq, float* __restrict__ outx){
  __shared__ float X[NN], Y[NN], Z[NN];
  __shared__ float QX[SS], QY[SS], QZ[SS];
  __shared__ u64 red[2][8];
  int b=blockIdx.x, t=threadIdx.x;
  const float* xb=xyz+(size_t)b*3*NN;
  for (int i=t;i<NN;i+=512){ X[i]=xb[i]; Y[i]=xb[NN+i]; Z[i]=xb[2*NN+i]; }
  __syncthreads();
  f32x2 px[4],py[4],pz[4],dd[4];
  #pragma unroll
  for (int k=0;k<4;k++){
    int i=t*8+2*k;
    px[k].x=X[i]; px[k].y=X[i+1];
    py[k].x=Y[i]; py[k].y=Y[i+1];
    pz[k].x=Z[i]; pz[k].y=Z[i+1];
    dd[k].x=1e10f; dd[k].y=1e10f;
  }
  int wv=t>>6, ln=t&63;
  int far=0;
  for (int s=0;s<SS;s++){
    float fx=X[far], fy=Y[far], fz=Z[far];
    if (t==0){ QX[s]=fx; QY[s]=fy; QZ[s]=fz; }
    f32x2 nfx, nfy, nfz;
    nfx.x=-fx; nfx.y=-fx; nfy.x=-fy; nfy.y=-fy; nfz.x=-fz; nfz.y=-fz;
    #pragma unroll
    for (int k=0;k<4;k++){
      f32x2 dx=pk_add(px[k],nfx);
      f32x2 xx=pk_mul(dx,dx);
      f32x2 dy=pk_add(py[k],nfy);
      f32x2 yy=pk_mul(dy,dy);
      f32x2 dz=pk_add(pz[k],nfz);
      f32x2 zz=pk_mul(dz,dz);
      f32x2 s1=pk_add(xx,yy);
      f32x2 d2=pk_add(s1,zz);
      dd[k].x=fminf(dd[k].x,d2.x);
      dd[k].y=fminf(dd[k].y,d2.y);
    }
    float m01=fmaxf(dd[0].x,dd[0].y), m23=fmaxf(dd[1].x,dd[1].y);
    float m45=fmaxf(dd[2].x,dd[2].y), m67=fmaxf(dd[3].x,dd[3].y);
    u32 m=__float_as_uint(fmaxf(fmaxf(m01,m23),fmaxf(m45,m67)));
    m=dppmax<0x111,0xf>(m);
    m=dppmax<0x112,0xf>(m);
    m=dppmax<0x114,0xf>(m);
    m=dppmax<0x118,0xf>(m);
    u32 r15=(u32)__builtin_amdgcn_readlane((int)m,15);
    u32 r31=(u32)__builtin_amdgcn_readlane((int)m,31);
    u32 r47=(u32)__builtin_amdgcn_readlane((int)m,47);
    u32 r63=(u32)__builtin_amdgcn_readlane((int)m,63);
    u32 ab = r15>r31 ? r15 : r31;
    u32 cd = r47>r63 ? r47 : r63;
    u32 wmax = ab>cd ? ab : cd;
    int lj=8;
    if (__float_as_uint(dd[3].y)==wmax) lj=7;
    if (__float_as_uint(dd[3].x)==wmax) lj=6;
    if (__float_as_uint(dd[2].y)==wmax) lj=5;
    if (__float_as_uint(dd[2].x)==wmax) lj=4;
    if (__float_as_uint(dd[1].y)==wmax) lj=3;
    if (__float_as_uint(dd[1].x)==wmax) lj=2;
    if (__float_as_uint(dd[0].y)==wmax) lj=1;
    if (__float_as_uint(dd[0].x)==wmax) lj=0;
    u64 ball=__ballot(lj<8);
    u32 wl=(u32)__builtin_ctzll(ball);
    int gi=t*8+lj;
    u32 widx=(u32)__builtin_amdgcn_readlane(gi,wl);
    int pb=s&1;
    if (ln==0) red[pb][wv]=((u64)wmax<<32)|(u32)(4095u-widx);
    __syncthreads();
    const double* rd=(const double*)&red[pb][0];
    double g=fmax(fmax(fmax(rd[0],rd[1]),fmax(rd[2],rd[3])),
                  fmax(fmax(rd[4],rd[5]),fmax(rd[6],rd[7])));
    far=4095-(int)(__double_as_longlong(g)&0xFFFull);
  }
  __syncthreads();
  for (int i=t;i<SS;i+=512){
    float qx=QX[i], qy=QY[i], qz=QZ[i];
    float* q=&fpsq[((size_t)b*SS+i)*3]; q[0]=qx; q[1]=qy; q[2]=qz;
    outx[b*3*SS+i]=qx; outx[b*3*SS+SS+i]=qy; outx[b*3*SS+2*SS+i]=qz;
  }
}

// ---------------- KNN: top-32 of 4096 per query, one wave/query ----------------
#define KSTR 68
__global__ __launch_bounds__(256) void k_knn(const float* __restrict__ xyz, const float* __restrict__ fpsq,
                                             int* __restrict__ kidx){
  extern __shared__ char smem[];
  float* xs=(float*)smem;
  float* ys=xs+64*KSTR;
  float* zs=ys+64*KSTR;
  float* pn=zs+64*KSTR;
  int blk=blockIdx.x; int b=blk>>8; int s0=(blk&255)*4;
  const float* xb=xyz+(size_t)b*3*NN;
  for (int i=threadIdx.x;i<NN;i+=256){
    float x=xb[i],y=xb[NN+i],z=xb[2*NN+i];
    int slot=(i>>6)*KSTR+(i&63);
    xs[slot]=x; ys[slot]=y; zs[slot]=z;
    pn[slot]=__fadd_rn(__fadd_rn(__fmul_rn(x,x),__fmul_rn(y,y)),__fmul_rn(z,z));
  }
  __syncthreads();
  int wv=threadIdx.x>>6, ln=threadIdx.x&63;
  int s=s0+wv;
  const float* q=&fpsq[((size_t)b*SS+s)*3];
  float qx=q[0],qy=q[1],qz=q[2];
  float qn=__fadd_rn(__fadd_rn(__fmul_rn(qx,qx),__fmul_rn(qy,qy)),__fmul_rn(qz,qz));
  f32x2 qxx,qyy,qzz,qnn,mtwo;
  qxx.x=qx;qxx.y=qx; qyy.x=qy;qyy.y=qy; qzz.x=qz;qzz.y=qz; qnn.x=qn;qnn.y=qn;
  mtwo.x=-2.f; mtwo.y=-2.f;
  const float4* Xp=(const float4*)(xs+ln*KSTR);
  const float4* Yp=(const float4*)(ys+ln*KSTR);
  const float4* Zp=(const float4*)(zs+ln*KSTR);
  const float4* Pp=(const float4*)(pn+ln*KSTR);
  int base=ln*64;
  u64 v[64];
  #pragma unroll
  for (int g=0;g<16;g++){
    float4 x4=Xp[g], y4=Yp[g], z4=Zp[g], p4=Pp[g];
    #pragma unroll
    for (int h=0;h<2;h++){
      f32x2 px2,py2,pz2,pn2;
      if (h==0){ px2.x=x4.x;px2.y=x4.y; py2.x=y4.x;py2.y=y4.y; pz2.x=z4.x;pz2.y=z4.y; pn2.x=p4.x;pn2.y=p4.y; }
      else     { px2.x=x4.z;px2.y=x4.w; py2.x=y4.z;py2.y=y4.w; pz2.x=z4.z;pz2.y=z4.w; pn2.x=p4.z;pn2.y=p4.w; }
      f32x2 m1=pk_mul(qxx,px2);
      f32x2 mm=pk_mul(qyy,py2);
      f32x2 a1=pk_add(m1,mm);
      f32x2 m3=pk_mul(qzz,pz2);
      f32x2 dt=pk_add(a1,m3);
      f32x2 qp=pk_add(qnn,pn2);
      f32x2 nd=pk_mul(dt,mtwo);
      f32x2 d2=pk_add(qp,nd);
      #pragma unroll
      for (int e=0;e<2;e++){
        u32 bu=__float_as_uint(e?d2.y:d2.x);
        bu = ((int)bu<0)? ~bu : (bu|0x80000000u);
        v[g*4+h*2+e]=((u64)bu<<32)|(u32)(base+g*4+h*2+e);
      }
    }
  }
  u64 cand[8];
  #pragma unroll
  for (int gg=0;gg<8;gg++){
    u64 c=v[gg*8];
    #pragma unroll
    for (int j=1;j<8;j++){ u64 x=v[gg*8+j]; c = x<c?x:c; }
    cand[gg]=c;
  }
  u64 best=cand[0];
  #pragma unroll
  for (int gg=1;gg<8;gg++){ u64 x=cand[gg]; best = x<best?x:best; }
  int my=0;
  #pragma unroll 1
  for (int r=0;r<KK;r++){
    u64 w=best;
    #pragma unroll
    for (int m=1;m<64;m<<=1){ u64 o=__shfl_xor(w,m,64); w = o<w?o:w; }
    if (ln==r) my=(int)(w&0xFFFull);
    if (best==w){
      #pragma unroll
      for (int gg=0;gg<8;gg++){
        if (cand[gg]==w){
          u64 c=~0ull;
          #pragma unroll
          for (int j=0;j<8;j++){ u64 x=v[gg*8+j]; x = x>w ? x : ~0ull; c = x<c?x:c; }
          cand[gg]=c;
        }
      }
      u64 nb=cand[0];
      #pragma unroll
      for (int gg=1;gg<8;gg++){ u64 x=cand[gg]; nb = x<nb?x:nb; }
      best=nb;
    }
  }
  if (ln<KK) kidx[(((size_t)b*SS+s)<<5)+ln]=my;
}

// ---------------- layer 0: gather + 67->64 + wnet 3->8 (+fused stats) ----------------
__global__ __launch_bounds__(256) void k_l0(const float* __restrict__ xyz, const float* __restrict__ ft,
    const float* __restrict__ fpsq, const int* __restrict__ kidx,
    const float* __restrict__ w0t, const float* __restrict__ wt0,
    u16* __restrict__ y0, float* __restrict__ wl0, float* __restrict__ statsf){
  __shared__ u16 ytile[256][64];
  __shared__ float pS[4][64], pQ[4][64];
  __shared__ float pWS[4][8], pWQ[4][8];
  int t=threadIdx.x; int wv=t>>6, ln=t&63;
  int p=blockIdx.x*256+t;
  int b=p>>15;
  int site=p>>5;
  int j=kidx[p];
  const float* xb=xyz+(size_t)b*3*NN;
  const float* q=fpsq+(size_t)site*3;
  float gx=xb[j]-q[0], gy=xb[NN+j]-q[1], gz=xb[2*NN+j]-q[2];
  float acc[64];
  #pragma unroll
  for (int c=0;c<64;c++) acc[c]=fmaf(gx,w0t[c],fmaf(gy,w0t[64+c],gz*w0t[128+c]));
  const float4* fr=(const float4*)(ft+((size_t)b*NN+j)*64);
  #pragma unroll 1
  for (int kb=0;kb<4;kb++){
    float4 r0=fr[kb*4+0], r1=fr[kb*4+1], r2=fr[kb*4+2], r3=fr[kb*4+3];
    float ch[16]={r0.x,r0.y,r0.z,r0.w,r1.x,r1.y,r1.z,r1.w,r2.x,r2.y,r2.z,r2.w,r3.x,r3.y,r3.z,r3.w};
    const float* wb=w0t+(3+kb*16)*64;
    #pragma unroll
    for (int kk=0;kk<16;kk++){
      #pragma unroll
      for (int c=0;c<64;c++) acc[c]=fmaf(ch[kk],wb[kk*64+c],acc[c]);
    }
  }
  u16* yr=y0+(size_t)p*64;
  #pragma unroll
  for (int c8=0;c8<8;c8++){
    uint4 pk=pack8(&acc[c8*8]);
    ((uint4*)yr)[c8]=pk;
    *((uint4*)&ytile[t][c8*8])=pk;
  }
  float wa[8];
  #pragma unroll
  for (int o=0;o<8;o++) wa[o]=fmaf(gx,wt0[o],fmaf(gy,wt0[8+o],gz*wt0[16+o]));
  float4* wr=(float4*)(wl0+(size_t)p*8);
  wr[0]=make_float4(wa[0],wa[1],wa[2],wa[3]);
  wr[1]=make_float4(wa[4],wa[5],wa[6],wa[7]);
  // wnet stats via DPP
  float wS[8],wQ[8];
  #pragma unroll
  for (int o=0;o<8;o++){
    wS[o]=rl63(dppsum(wa[o]));
    wQ[o]=rl63(dppsum(wa[o]*wa[o]));
  }
  if (ln==0){
    #pragma unroll
    for (int o=0;o<8;o++){ pWS[wv][o]=wS[o]; pWQ[wv][o]=wQ[o]; }
  }
  __syncthreads();
  // y column stats from rounded values
  {
    int c=t&63, rg=t>>6;
    float S=0.f,Q=0.f;
    #pragma unroll 16
    for (int r=0;r<64;r++){
      float v=bf2f((u32)ytile[rg*64+r][c]);
      S+=v; Q=fmaf(v,v,Q);
    }
    pS[rg][c]=S; pQ[rg][c]=Q;
  }
  __syncthreads();
  if (t<64){
    float S=pS[0][t]+pS[1][t]+pS[2][t]+pS[3][t];
    float Q=pQ[0][t]+pQ[1][t]+pQ[2][t]+pQ[3][t];
    atomicAdd(&statsf[2*(ST_Y0+t)],S); atomicAdd(&statsf[2*(ST_Y0+t)+1],Q);
  } else if (t<72){
    int c=t-64;
    float S=pWS[0][c]+pWS[1][c]+pWS[2][c]+pWS[3][c];
    float Q=pWQ[0][c]+pWQ[1][c]+pWQ[2][c]+pWQ[3][c];
    atomicAdd(&statsf[2*(ST_W0+c)],S); atomicAdd(&statsf[2*(ST_W0+c)+1],Q);
  }
}

// ---------------- layer 1: BN0+relu -> 64->64 ; wnet BN+relu 8->8 (+fused stats) ----------------
__global__ __launch_bounds__(256) void k_l1(const u16* __restrict__ y0, const float* __restrict__ wl0,
    const float* __restrict__ w1t, const float* __restrict__ wt1,
    const float* __restrict__ statsf,
    const float* __restrict__ g0v, const float* __restrict__ be0v,
    const float* __restrict__ wg0v, const float* __restrict__ wbe0v,
    u16* __restrict__ y1, float* __restrict__ wl1, float* __restrict__ statso){
  __shared__ float A0[64],C0[64],AW[8],CW[8];
  __shared__ u16 ytile[256][64];
  __shared__ float pS[4][64], pQ[4][64];
  __shared__ float pWS[4][8], pWQ[4][8];
  int t=threadIdx.x; int wv=t>>6, ln=t&63;
  if (t<64){
    float sm=statsf[(ST_Y0+t)*2], sq=statsf[(ST_Y0+t)*2+1];
    float mean=sm*(1.f/PP), var=fmaxf(sq*(1.f/PP)-mean*mean,0.f);
    float a=g0v[t]*rsqrtf(var+1e-5f); A0[t]=a; C0[t]=be0v[t]-mean*a;
  } else if (t<72){
    int c=t-64;
    float sm=statsf[(ST_W0+c)*2], sq=statsf[(ST_W0+c)*2+1];
    float mean=sm*(1.f/PP), var=fmaxf(sq*(1.f/PP)-mean*mean,0.f);
    float a=wg0v[c]*rsqrtf(var+1e-5f); AW[c]=a; CW[c]=wbe0v[c]-mean*a;
  }
  __syncthreads();
  int p=blockIdx.x*256+t;
  const uint4* yr=(const uint4*)(y0+(size_t)p*64);
  float acc[64];
  #pragma unroll
  for (int c=0;c<64;c++) acc[c]=0.f;
  #pragma unroll 1
  for (int kb=0;kb<4;kb++){
    uint4 r0=yr[kb*2], r1=yr[kb*2+1];
    float ch[16];
    unp8_aff(r0,A0,C0,kb*16,ch);
    unp8_aff(r1,A0,C0,kb*16+8,ch+8);
    const float* wb=w1t+kb*16*64;
    #pragma unroll
    for (int kk=0;kk<16;kk++){
      #pragma unroll
      for (int c=0;c<64;c++) acc[c]=fmaf(ch[kk],wb[kk*64+c],acc[c]);
    }
  }
  u16* yo=y1+(size_t)p*64;
  #pragma unroll
  for (int c8=0;c8<8;c8++){
    uint4 pk=pack8(&acc[c8*8]);
    ((uint4*)yo)[c8]=pk;
    *((uint4*)&ytile[t][c8*8])=pk;
  }
  const float4* wvp=(const float4*)(wl0+(size_t)p*8);
  float4 v0=wvp[0], v1=wvp[1];
  float wi[8]={v0.x,v0.y,v0.z,v0.w,v1.x,v1.y,v1.z,v1.w};
  float wo[8];
  #pragma unroll
  for (int o=0;o<8;o++) wo[o]=0.f;
  #pragma unroll
  for (int k=0;k<8;k++){
    float xr=fmaxf(fmaf(wi[k],AW[k],CW[k]),0.f);
    #pragma unroll
    for (int o=0;o<8;o++) wo[o]=fmaf(xr,wt1[k*8+o],wo[o]);
  }
  float4* wr=(float4*)(wl1+(size_t)p*8);
  wr[0]=make_float4(wo[0],wo[1],wo[2],wo[3]);
  wr[1]=make_float4(wo[4],wo[5],wo[6],wo[7]);
  float wS[8],wQ[8];
  #pragma unroll
  for (int o=0;o<8;o++){
    wS[o]=rl63(dppsum(wo[o]));
    wQ[o]=rl63(dppsum(wo[o]*wo[o]));
  }
  if (ln==0){
    #pragma unroll
    for (int o=0;o<8;o++){ pWS[wv][o]=wS[o]; pWQ[wv][o]=wQ[o]; }
  }
  __syncthreads();
  {
    int c=t&63, rg=t>>6;
    float S=0.f,Q=0.f;
    #pragma unroll 16
    for (int r=0;r<64;r++){
      float v=bf2f((u32)ytile[rg*64+r][c]);
      S+=v; Q=fmaf(v,v,Q);
    }
    pS[rg][c]=S; pQ[rg][c]=Q;
  }
  __syncthreads();
  if (t<64){
    float S=pS[0][t]+pS[1][t]+pS[2][t]+pS[3][t];
    float Q=pQ[0][t]+pQ[1][t]+pQ[2][t]+pQ[3][t];
    atomicAdd(&statso[2*(ST_Y1+t)],S); atomicAdd(&statso[2*(ST_Y1+t)+1],Q);
  } else if (t<72){
    int c=t-64;
    float S=pWS[0][c]+pWS[1][c]+pWS[2][c]+pWS[3][c];
    float Q=pWQ[0][c]+pWQ[1][c]+pWQ[2][c]+pWQ[3][c];
    atomicAdd(&statso[2*(ST_W1+c)],S); atomicAdd(&statso[2*(ST_W1+c)+1],Q);
  }
}

// ---------------- layer 2: BN1+relu -> 64->128 ; wnet BN+relu 8->16 (+fused stats) ----------------
__global__ __launch_bounds__(256) void k_l2(const u16* __restrict__ y1, const float* __restrict__ wl1,
    const float* __restrict__ w2t, const float* __restrict__ wt2,
    const float* __restrict__ statsf,
    const float* __restrict__ g1v, const float* __restrict__ be1v,
    const float* __restrict__ wg1v, const float* __restrict__ wbe1v,
    u16* __restrict__ y2, float* __restrict__ wl2, float* __restrict__ statso){
  __shared__ float A1[64],C1[64],AW[8],CW[8];
  __shared__ u16 ytile[256][64];
  __shared__ float pS[4][64], pQ[4][64];
  __shared__ float pWS[4][16], pWQ[4][16];
  int t=threadIdx.x; int wv=t>>6, ln=t&63;
  if (t<64){
    float sm=statsf[(ST_Y1+t)*2], sq=statsf[(ST_Y1+t)*2+1];
    float mean=sm*(1.f/PP), var=fmaxf(sq*(1.f/PP)-mean*mean,0.f);
    float a=g1v[t]*rsqrtf(var+1e-5f); A1[t]=a; C1[t]=be1v[t]-mean*a;
  } else if (t<72){
    int c=t-64;
    float sm=statsf[(ST_W1+c)*2], sq=statsf[(ST_W1+c)*2+1];
    float mean=sm*(1.f/PP), var=fmaxf(sq*(1.f/PP)-mean*mean,0.f);
    float a=wg1v[c]*rsqrtf(var+1e-5f); AW[c]=a; CW[c]=wbe1v[c]-mean*a;
  }
  __syncthreads();
  int p=blockIdx.x*256+t;
  const uint4* yr=(const uint4*)(y1+(size_t)p*64);
  #pragma unroll 1
  for (int h=0;h<2;h++){
    float acc[64];
    #pragma unroll
    for (int c=0;c<64;c++) acc[c]=0.f;
    #pragma unroll 1
    for (int kb=0;kb<4;kb++){
      uint4 r0=yr[kb*2], r1=yr[kb*2+1];
      float ch[16];
      unp8_aff(r0,A1,C1,kb*16,ch);
      unp8_aff(r1,A1,C1,kb*16+8,ch+8);
      const float* wb=w2t+(size_t)kb*16*128+h*64;
      #pragma unroll
      for (int kk=0;kk<16;kk++){
        #pragma unroll
        for (int c=0;c<64;c++) acc[c]=fmaf(ch[kk],wb[kk*128+c],acc[c]);
      }
    }
    u16* yo=y2+(size_t)p*128+h*64;
    #pragma unroll
    for (int c8=0;c8<8;c8++){
      uint4 pk=pack8(&acc[c8*8]);
      ((uint4*)yo)[c8]=pk;
      *((uint4*)&ytile[t][c8*8])=pk;
    }
    __syncthreads();
    {
      int c=t&63, rg=t>>6;
      float S=0.f,Q=0.f;
      #pragma unroll 16
      for (int r=0;r<64;r++){
        float v=bf2f((u32)ytile[rg*64+r][c]);
        S+=v; Q=fmaf(v,v,Q);
      }
      pS[rg][c]=S; pQ[rg][c]=Q;
    }
    __syncthreads();
    if (t<64){
      float S=pS[0][t]+pS[1][t]+pS[2][t]+pS[3][t];
      float Q=pQ[0][t]+pQ[1][t]+pQ[2][t]+pQ[3][t];
      atomicAdd(&statso[2*(ST_Y2+h*64+t)],S); atomicAdd(&statso[2*(ST_Y2+h*64+t)+1],Q);
    }
    __syncthreads();   // protect ytile/pS reuse across h
  }
  // wnet 8->16
  const float4* wvp=(const float4*)(wl1+(size_t)p*8);
  float4 v0=wvp[0], v1=wvp[1];
  float wi[8]={v0.x,v0.y,v0.z,v0.w,v1.x,v1.y,v1.z,v1.w};
  float wo[16];
  #pragma unroll
  for (int o=0;o<16;o++) wo[o]=0.f;
  #pragma unroll
  for (int k=0;k<8;k++){
    float xr=fmaxf(fmaf(wi[k],AW[k],CW[k]),0.f);
    #pragma unroll
    for (int o=0;o<16;o++) wo[o]=fmaf(xr,wt2[k*16+o],wo[o]);
  }
  float4* wr=(float4*)(wl2+(size_t)p*16);
  wr[0]=make_float4(wo[0],wo[1],wo[2],wo[3]);
  wr[1]=make_float4(wo[4],wo[5],wo[6],wo[7]);
  wr[2]=make_float4(wo[8],wo[9],wo[10],wo[11]);
  wr[3]=make_float4(wo[12],wo[13],wo[14],wo[15]);
  float wS[16],wQ[16];
  #pragma unroll
  for (int o=0;o<16;o++){
    wS[o]=rl63(dppsum(wo[o]));
    wQ[o]=rl63(dppsum(wo[o]*wo[o]));
  }
  if (ln==0){
    #pragma unroll
    for (int o=0;o<16;o++){ pWS[wv][o]=wS[o]; pWQ[wv][o]=wQ[o]; }
  }
  __syncthreads();
  if (t<16){
    float S=pWS[0][t]+pWS[1][t]+pWS[2][t]+pWS[3][t];
    float Q=pWQ[0][t]+pWQ[1][t]+pWQ[2][t]+pWQ[3][t];
    atomicAdd(&statso[2*(ST_W2+t)],S); atomicAdd(&statso[2*(ST_W2+t)+1],Q);
  }
}

// ---------------- agg: per site, BN2+relu both, outer-product pooled over k ----------------
__global__ __launch_bounds__(256) void k_agg(const u16* __restrict__ y2, const float* __restrict__ wl2,
    const float* __restrict__ statsf,
    const float* __restrict__ g2v, const float* __restrict__ be2v,
    const float* __restrict__ wg2v, const float* __restrict__ wbe2v,
    u16* __restrict__ agg){
  __shared__ float A2[128],C2[128],AW[16],CW[16];
  __shared__ float nf[32*128];
  __shared__ float wt[32*16];
  int site=blockIdx.x; int t=threadIdx.x;
  if (t<128){
    float sm=statsf[(ST_Y2+t)*2], sq=statsf[(ST_Y2+t)*2+1];
    float mean=sm*(1.f/PP), var=fmaxf(sq*(1.f/PP)-mean*mean,0.f);
    float a=g2v[t]*rsqrtf(var+1e-5f); A2[t]=a; C2[t]=be2v[t]-mean*a;
  } else if (t<144){
    int c=t-128;
    float sm=statsf[(ST_W2+c)*2], sq=statsf[(ST_W2+c)*2+1];
    float mean=sm*(1.f/PP), var=fmaxf(sq*(1.f/PP)-mean*mean,0.f);
    float a=wg2v[c]*rsqrtf(var+1e-5f); AW[c]=a; CW[c]=wbe2v[c]-mean*a;
  }
  __syncthreads();
  const uint4* src=(const uint4*)(y2+(size_t)site*32*128);
  #pragma unroll
  for (int it=0;it<2;it++){
    int idx=t+it*256;
    uint4 r=src[idx];
    int base=(idx*8)&127; int kq=(idx*8)>>7;
    unp8_aff(r,A2,C2,base,&nf[kq*128+base]);
  }
  #pragma unroll
  for (int it=0;it<2;it++){
    int i=t+it*256;
    float x=wl2[(size_t)site*512+i]; int c=i&15;
    wt[i]=fmaxf(fmaf(x,AW[c],CW[c]),0.f);
  }
  __syncthreads();
  int d=t>>1, cb=(t&1)*8;
  float acc[8];
  #pragma unroll
  for (int e=0;e<8;e++) acc[e]=0.f;
  #pragma unroll 4
  for (int kq=0;kq<32;kq++){
    float nv=nf[kq*128+d];
    #pragma unroll
    for (int e=0;e<8;e++) acc[e]=fmaf(nv,wt[kq*16+cb+e],acc[e]);
  }
  ((uint4*)(agg+(size_t)site*2048))[t]=pack8(acc);
}

// ---------------- linear: [8192 x 2048] @ lw^T -> [8192 x 128], fused lin-stats ----------------
__global__ __launch_bounds__(256) void k_lin(const u16* __restrict__ agg, const float* __restrict__ lw,
                                             float* __restrict__ lin, float* __restrict__ outst){
  __shared__ float As[32][33];
  __shared__ float Bs[32][128];
  __shared__ float stS[8][132], stQ[8][132];
  int s0=blockIdx.x*32; int t=threadIdx.x;
  int tx=t&31, ty=t>>5;
  float acc[4][4];
  #pragma unroll
  for (int i=0;i<4;i++){
    #pragma unroll
    for (int jj=0;jj<4;jj++) acc[i][jj]=0.f;
  }
  for (int kb=0;kb<2048;kb+=32){
    {
      int row=t>>3, kc=(t&7)*4;
      uint2 raw=*(const uint2*)(agg+((size_t)(s0+row))*2048+kb+kc);
      As[row][kc  ]=bf2f(raw.x&0xffffu); As[row][kc+1]=bf2f(raw.x>>16);
      As[row][kc+2]=bf2f(raw.y&0xffffu); As[row][kc+3]=bf2f(raw.y>>16);
    }
    {
      int o=t>>1, ks=(t&1)*16;
      const float* lr=lw+(size_t)o*2048+kb+ks;
      #pragma unroll
      for (int i=0;i<16;i+=4){
        float4 r=*(const float4*)(lr+i);
        Bs[ks+i][o]=r.x; Bs[ks+i+1][o]=r.y; Bs[ks+i+2][o]=r.z; Bs[ks+i+3][o]=r.w;
      }
    }
    __syncthreads();
    #pragma unroll 8
    for (int kk=0;kk<32;kk++){
      float av[4];
      #pragma unroll
      for (int i=0;i<4;i++) av[i]=As[ty*4+i][kk];
      float4 bv=*(const float4*)(&Bs[kk][tx*4]);
      #pragma unroll
      for (int i=0;i<4;i++){
        acc[i][0]=fmaf(av[i],bv.x,acc[i][0]);
        acc[i][1]=fmaf(av[i],bv.y,acc[i][1]);
        acc[i][2]=fmaf(av[i],bv.z,acc[i][2]);
        acc[i][3]=fmaf(av[i],bv.w,acc[i][3]);
      }
    }
    __syncthreads();
  }
  #pragma unroll
  for (int i=0;i<4;i++){
    float4 o4=make_float4(acc[i][0],acc[i][1],acc[i][2],acc[i][3]);
    *(float4*)(lin+((size_t)(s0+ty*4+i))*128+tx*4)=o4;
  }
  #pragma unroll
  for (int jj=0;jj<4;jj++){
    float a0=acc[0][jj],a1=acc[1][jj],a2=acc[2][jj],a3=acc[3][jj];
    stS[ty][tx*4+jj]=(a0+a1)+(a2+a3);
    stQ[ty][tx*4+jj]=fmaf(a3,a3,fmaf(a2,a2,fmaf(a1,a1,a0*a0)));
  }
  __syncthreads();
  if (t<128){
    float S=0.f,Q=0.f;
    #pragma unroll
    for (int k=0;k<8;k++){ S+=stS[k][t]; Q+=stQ[k][t]; }
    atomicAdd(&outst[2*t],S); atomicAdd(&outst[2*t+1],Q);
  }
}

// ---------------- final BN + relu + transpose -> out [B,128,S] ----------------
__global__ __launch_bounds__(256) void k_out(const float* __restrict__ lin, const float* __restrict__ statsf,
    const float* __restrict__ lg, const float* __restrict__ lbe, float* __restrict__ outf){
  int t=blockIdx.x*256+threadIdx.x;
  int s4=(t&255)*4; int o=(t>>8)&127; int b=t>>15;
  float sm=statsf[(ST_LIN+o)*2], sq=statsf[(ST_LIN+o)*2+1];
  float mean=sm*(1.f/8192.f), var=fmaxf(sq*(1.f/8192.f)-mean*mean,0.f);
  float a=lg[o]*rsqrtf(var+1e-5f), cc=lbe[o]-mean*a;
  float v0=lin[((size_t)b*SS+s4+0)*128+o];
  float v1=lin[((size_t)b*SS+s4+1)*128+o];
  float v2=lin[((size_t)b*SS+s4+2)*128+o];
  float v3=lin[((size_t)b*SS+s4+3)*128+o];
  float4 r=make_float4(fmaxf(fmaf(v0,a,cc),0.f),fmaxf(fmaf(v1,a,cc),0.f),
                       fmaxf(fmaf(v2,a,cc),0.f),fmaxf(fmaf(v3,a,cc),0.f));
  *(float4*)(outf+((size_t)b*128+o)*SS+s4)=r;
}

extern "C" void kernel_launch(void* const* d_in, const int* in_sizes, int n_in,
                              void* d_out, int out_size, void* d_ws, size_t ws_size,
                              hipStream_t stream){
  (void)in_sizes;(void)n_in;(void)out_size;(void)ws_size;
  const float* xyz =(const float*)d_in[0];
  const float* feat=(const float*)d_in[1];
  const float* w0=(const float*)d_in[2];  const float* g0=(const float*)d_in[4];  const float* be0=(const float*)d_in[5];
  const float* w1=(const float*)d_in[6];  const float* g1=(const float*)d_in[8];  const float* be1=(const float*)d_in[9];
  const float* w2=(const float*)d_in[10]; const float* g2=(const float*)d_in[12]; const float* be2=(const float*)d_in[13];
  const float* ww0=(const float*)d_in[14]; const float* wg0=(const float*)d_in[16]; const float* wbe0=(const float*)d_in[17];
  const float* ww1=(const float*)d_in[18]; const float* wg1=(const float*)d_in[20]; const float* wbe1=(const float*)d_in[21];
  const float* ww2=(const float*)d_in[22]; const float* wg2=(const float*)d_in[24]; const float* wbe2=(const float*)d_in[25];
  const float* lw=(const float*)d_in[26]; const float* lg=(const float*)d_in[28]; const float* lbe=(const float*)d_in[29];
  float* out=(float*)d_out;
  char* ws=(char*)d_ws;

  size_t cur=0;
  auto alloc=[&](size_t bytes)->size_t{ cur=(cur+255)&~(size_t)255; size_t o=cur; cur+=bytes; return o; };
  size_t o_stats=alloc(4096);
  size_t o_w0t =alloc(67*64*4);
  size_t o_w1t =alloc(64*64*4);
  size_t o_w2t =alloc(64*128*4);
  size_t o_wt0 =alloc(3*8*4);
  size_t o_wt1 =alloc(8*8*4);
  size_t o_wt2 =alloc(8*16*4);
  size_t o_fpsq=alloc((size_t)BB*SS*3*4);
  size_t o_kidx=alloc((size_t)PP*4);
  size_t o_ft  =alloc((size_t)BB*NN*64*4);
  size_t o_y0  =alloc((size_t)PP*64*2);
  size_t o_y1  =alloc((size_t)PP*64*2);
  size_t o_y2  =alloc((size_t)PP*128*2);
  size_t o_wl0 =alloc((size_t)PP*8*4);
  size_t o_wl1 =alloc((size_t)PP*8*4);
  size_t o_wl2 =alloc((size_t)PP*16*4);
  size_t o_agg =alloc((size_t)8192*2048*2);
  size_t o_lin =alloc((size_t)8192*128*4);

  float* statsf=(float*)(ws+o_stats);
  float* w0t=(float*)(ws+o_w0t); float* w1t=(float*)(ws+o_w1t); float* w2t=(float*)(ws+o_w2t);
  float* wt0=(float*)(ws+o_wt0); float* wt1=(float*)(ws+o_wt1); float* wt2=(float*)(ws+o_wt2);
  float* fpsq=(float*)(ws+o_fpsq); int* kidx=(int*)(ws+o_kidx);
  float* ft=(float*)(ws+o_ft);
  u16* y0=(u16*)(ws+o_y0); u16* y1=(u16*)(ws+o_y1); u16* y2=(u16*)(ws+o_y2);
  float* wl0=(float*)(ws+o_wl0); float* wl1=(float*)(ws+o_wl1); float* wl2=(float*)(ws+o_wl2);
  u16* agg=(u16*)(ws+o_agg); float* lin=(float*)(ws+o_lin);

  size_t knn_smem = (size_t)4*64*KSTR*4;             // 69632 B

  hipLaunchKernelGGL(k_featT,dim3(513),dim3(256),0,stream,feat,ft,
                     w0,w1,w2,ww0,ww1,ww2,w0t,w1t,w2t,wt0,wt1,wt2,statsf);
  hipLaunchKernelGGL(k_fps,dim3(BB),dim3(512),0,stream,xyz,fpsq,out);
  hipLaunchKernelGGL(k_knn,dim3(2048),dim3(256),knn_smem,stream,xyz,fpsq,kidx);
  hipLaunchKernelGGL(k_l0,dim3(PP/256),dim3(256),0,stream,xyz,ft,fpsq,kidx,w0t,wt0,y0,wl0,statsf);
  hipLaunchKernelGGL(k_l1,dim3(PP/256),dim3(256),0,stream,y0,wl0,w1t,wt1,statsf,g0,be0,wg0,wbe0,y1,wl1,statsf);
  hipLaunchKernelGGL(k_l2,dim3(PP/256),dim3(256),0,stream,y1,wl1,w2t,wt2,statsf,g1,be1,wg1,wbe1,y2,wl2,statsf);
  hipLaunchKernelGGL(k_agg,dim3(8192),dim3(256),0,stream,y2,wl2,statsf,g2,be2,wg2,wbe2,agg);
  hipLaunchKernelGGL(k_lin,dim3(256),dim3(256),0,stream,agg,lw,lin,statsf+2*ST_LIN);
  hipLaunchKernelGGL(k_out,dim3(1024),dim3(256),0,stream,lin,statsf,lg,lbe,out+BB*3*SS);
}